// Round 6
// baseline (198.030 us; speedup 1.0000x reference)
//
#include <hip/hip_runtime.h>

// MQA fused layer, MI355X gfx950.
// B=4 T=4096 C=1024 H=16 D=64 W=128 NB=32.
// Pipeline: cvt(x)->bf16 | transpose-cvt weights | GEMM qkv (256^2 8-phase) |
//           RMS+RoPE q,k | V transpose | blocked sliding-window attention
//           (swapped-QK^T, in-register online softmax) | GEMM proj (256^2).

typedef __attribute__((ext_vector_type(8))) short short8;
typedef __attribute__((ext_vector_type(4))) float f32x4;
typedef __attribute__((ext_vector_type(16))) float f32x16;
typedef __attribute__((ext_vector_type(4))) unsigned uint4v;

#define DEV static __device__ __forceinline__

DEV unsigned short f2bf(float f) {           // fp32 -> bf16 RNE
  unsigned u = __builtin_bit_cast(unsigned, f);
  u += 0x7fffu + ((u >> 16) & 1u);
  return (unsigned short)(u >> 16);
}
DEV float bf2f(unsigned short s) {
  unsigned u = ((unsigned)s) << 16;
  return __builtin_bit_cast(float, u);
}
DEV unsigned cvtpk(float a, float b) {       // {bf16(a), bf16(b)} packed
  unsigned r;
  asm("v_cvt_pk_bf16_f32 %0, %1, %2" : "=v"(r) : "v"(a), "v"(b));
  return r;
}

DEV f32x4 mfma16(short8 a, short8 b, f32x4 c) {
  return __builtin_amdgcn_mfma_f32_16x16x32_bf16(a, b, c, 0, 0, 0);
}
DEV f32x16 mfma32(short8 a, short8 b, f32x16 c) {
  return __builtin_amdgcn_mfma_f32_32x32x16_bf16(a, b, c, 0, 0, 0);
}

// async global->LDS, 16B per lane
DEV void gload16(const void* g, void* l) {
  __builtin_amdgcn_global_load_lds(
      (const __attribute__((address_space(1))) unsigned int*)(unsigned long long)g,
      (__attribute__((address_space(3))) unsigned int*)(unsigned int)(unsigned long long)l,
      16, 0, 0);
}

// inline-asm ds_read_b128 on a raw 32-bit LDS byte address. Invisible to the
// compiler's alias analysis -> no auto-inserted vmcnt(0) against outstanding
// global_load_lds DMAs (the hazards are covered manually by barriers/waits).
DEV short8 dsr128(unsigned a) {
  short8 r;
  asm volatile("ds_read_b128 %0, %1" : "=v"(r) : "v"(a));
  return r;
}

#define BARRIER __builtin_amdgcn_s_barrier()
#define LGKM0  asm volatile("s_waitcnt lgkmcnt(0)" ::: "memory")
#define VMCNT4 asm volatile("s_waitcnt vmcnt(4)" ::: "memory")
// rule #18: required fence after LGKM0 so MFMAs aren't hoisted above the wait
// (their asm-ds_read operands are register-only deps the scheduler may move).
#define SCHED0 __builtin_amdgcn_sched_barrier(0)

// ---------------- kernel: f32 -> bf16 elementwise ----------------
__global__ __launch_bounds__(256) void k_cvt(const float* __restrict__ in,
                                             short* __restrict__ out, int n4) {
  int i = blockIdx.x * 256 + threadIdx.x;
  if (i >= n4) return;
  float4 v = ((const float4*)in)[i];
  short4 o;
  o.x = (short)f2bf(v.x); o.y = (short)f2bf(v.y);
  o.z = (short)f2bf(v.z); o.w = (short)f2bf(v.w);
  ((short4*)out)[i] = o;
}

// ---------------- kernel: W (KxN f32) -> Wt (NxK bf16) ----------------
__global__ __launch_bounds__(256) void k_tcvt(const float* __restrict__ W,
                                              short* __restrict__ Wt, int K, int N) {
  __shared__ float tl[32][33];
  int tx = threadIdx.x & 31, ty = threadIdx.x >> 5;   // 32 x 8
  int k0 = blockIdx.x * 32, n0 = blockIdx.y * 32;
#pragma unroll
  for (int i = 0; i < 4; ++i)
    tl[ty + i * 8][tx] = W[(size_t)(k0 + ty + i * 8) * N + n0 + tx];
  __syncthreads();
#pragma unroll
  for (int i = 0; i < 4; ++i)
    Wt[(size_t)(n0 + ty + i * 8) * K + k0 + tx] = (short)f2bf(tl[tx][ty + i * 8]);
}

// ---------------- kernel: 256x256x64 bf16 GEMM, 8-phase schedule ------------
// A: MxK row-major bf16. Bt: NxK row-major bf16. C: MxN (bf16 or f32).
// 8 waves (2M x 4N), per-wave C = 128x64. LDS 128 KiB: [dbuf][A/B][half][128][64],
// chunk-XOR swizzled (chunk' = chunk ^ (row&7)), staged via global_load_lds with
// pre-swizzled global source. Per K-tile: 4 phases; counted vmcnt(4) per tile.
// Fragment loads are inline-asm ds_read_b128 (see dsr128 note).
__global__ __launch_bounds__(512, 2) void k_gemm256(const short* __restrict__ A,
                                                    const short* __restrict__ Bt,
                                                    void* __restrict__ Cout,
                                                    int M, int N, int K, int outBf16) {
  __shared__ short sm[65536];                       // 128 KiB
  int nbn = N >> 8;
  int nwg = (M >> 8) * nbn;
  int bid = blockIdx.x;
  int swz = (bid & 7) * (nwg >> 3) + (bid >> 3);    // XCD swizzle (nwg % 8 == 0)
  int bm = swz / nbn, bn = swz % nbn;
  int tid = threadIdx.x, wid = tid >> 6, lane = tid & 63;
  int wm = wid >> 2, wn = wid & 3;
  int lo = lane & 15, hi = lane >> 4;
  int NT = K >> 6;                                  // # K-tiles (BK=64)

  // staging: thread covers (row r0, chunk dc) and (r0+64, dc) of a 128x8-chunk half
  int r0 = tid >> 3, dc = tid & 7;
  int sc = dc ^ (r0 & 7);                           // pre-swizzled source chunk
  const short* aS0 = A  + (size_t)(bm * 256 + r0) * K + sc * 8;        // half 0
  const short* bS0 = Bt + (size_t)(bn * 256 + r0) * K + sc * 8;
  size_t hstep = (size_t)128 * K;                   // half 1 = +128 rows

  // stage one half-tile: mat 0=A 1=B, half h, dbuf d, K-tile jt
  auto stage = [&](int jt, int mat, int h, int d) {
    const short* s = (mat ? bS0 : aS0) + (size_t)h * hstep + jt * 64;
    short* l = sm + d * 32768 + mat * 16384 + h * 8192;
    gload16(s,                     l + tid * 8);
    gload16(s + (size_t)64 * K,    l + 4096 + tid * 8);
  };

  // LDS base as 32-bit address (LDS aperture low-32 = LDS offset on gfx9+)
  unsigned smB = (unsigned)(unsigned long long)(void*)sm;
  // fragment byte offsets: row lo, chunk (kk*4+hi)^(lo&7)
  unsigned aRdB[2];
#pragma unroll
  for (int kk = 0; kk < 2; ++kk)
    aRdB[kk] = (unsigned)(lo * 128 + (((kk << 2) | hi) ^ (lo & 7)) * 16);

  short8 Afr[8][2];                                 // 8 Mfrag x 2 kk
  short8 Bfr[2][2];                                 // 2 live Nfrag x 2 kk
  f32x4 acc[8][4] = {};

  auto rdA = [&](int d, int m0) {
    unsigned base = smB + d * 65536 + wm * 16384;
#pragma unroll
    for (int m = 0; m < 4; ++m)
#pragma unroll
      for (int kk = 0; kk < 2; ++kk)
        Afr[m0 + m][kk] = dsr128(base + (m0 + m) * 2048 + aRdB[kk]);
  };
  auto rdB = [&](int d, int n0) {
    unsigned base = smB + d * 65536 + 32768 + (wn >> 1) * 16384 + (wn & 1) * 8192;
#pragma unroll
    for (int nf = 0; nf < 2; ++nf)
#pragma unroll
      for (int kk = 0; kk < 2; ++kk)
        Bfr[nf][kk] = dsr128(base + (n0 + nf) * 2048 + aRdB[kk]);
  };
  auto quad = [&](int m0, int n0) {                 // 16 MFMA: 4 Mfrag x 2 Nfrag x 2 kk
    __builtin_amdgcn_s_setprio(1);
#pragma unroll
    for (int m = 0; m < 4; ++m)
#pragma unroll
      for (int j = 0; j < 2; ++j)
#pragma unroll
        for (int kk = 0; kk < 2; ++kk)
          acc[m0 + m][n0 + j] = mfma16(Afr[m0 + m][kk], Bfr[j][kk], acc[m0 + m][n0 + j]);
    __builtin_amdgcn_s_setprio(0);
  };

  // prologue: tile0 all 4 halves (dbuf0), tile1 A0,B0 (dbuf1); keep 4 in flight
  stage(0, 0, 0, 0); stage(0, 1, 0, 0); stage(0, 0, 1, 0); stage(0, 1, 1, 0);
  if (NT > 1) { stage(1, 0, 0, 1); stage(1, 1, 0, 1); }
  VMCNT4;
  BARRIER;

#pragma unroll 2
  for (int jt = 0; jt < NT; ++jt) {
    int d = jt & 1;
    // ph0: read A M0-3 + B N0-1; stage (jt+1, A1)
    rdA(d, 0); rdB(d, 0);
    if (jt + 1 < NT) stage(jt + 1, 0, 1, d ^ 1);
    BARRIER; LGKM0; SCHED0;
    quad(0, 0);
    BARRIER;
    // ph1: read A M4-7; stage (jt+1, B1)
    rdA(d, 4);
    if (jt + 1 < NT) stage(jt + 1, 1, 1, d ^ 1);
    BARRIER; LGKM0; SCHED0;
    quad(4, 0);
    BARRIER;
    // ph2: read B N2-3; stage (jt+2, A0)
    rdB(d, 2);
    if (jt + 2 < NT) stage(jt + 2, 0, 0, d);
    BARRIER; LGKM0; SCHED0;
    quad(0, 2);
    BARRIER;
    // ph3: stage (jt+2, B0); counted vmcnt (never 0 in-loop)
    if (jt + 2 < NT) stage(jt + 2, 1, 0, d);
    VMCNT4;
    BARRIER;
    quad(4, 2);
    BARRIER;
  }

  // epilogue: C layout col = lane&15, row = (lane>>4)*4 + reg
  int row0 = bm * 256 + wm * 128 + hi * 4;
  int col0 = bn * 256 + wn * 64 + lo;
  if (outBf16) {
    short* C = (short*)Cout;
#pragma unroll
    for (int m = 0; m < 8; ++m)
#pragma unroll
      for (int nf = 0; nf < 4; ++nf)
#pragma unroll
        for (int r = 0; r < 4; ++r)
          C[(size_t)(row0 + m * 16 + r) * N + col0 + nf * 16] = (short)f2bf(acc[m][nf][r]);
  } else {
    float* C = (float*)Cout;
#pragma unroll
    for (int m = 0; m < 8; ++m)
#pragma unroll
      for (int nf = 0; nf < 4; ++nf)
#pragma unroll
        for (int r = 0; r < 4; ++r)
          C[(size_t)(row0 + m * 16 + r) * N + col0 + nf * 16] = acc[m][nf][r];
  }
}

// ---------------- kernel: RMSNorm + RoPE for q (16 heads) and k ----------------
// 256 threads = 4 waves; each wave (64 lanes = D) handles one token
__global__ __launch_bounds__(256) void k_qk(const short* __restrict__ qkvb,
                                            const int* __restrict__ pos,
                                            const float* __restrict__ qw,
                                            const float* __restrict__ kw,
                                            short* __restrict__ qb,
                                            short* __restrict__ kb) {
  int bt = blockIdx.x * 4 + (threadIdx.x >> 6);    // b*4096 + t
  int t = bt & 4095, b = bt >> 12;
  int d = threadIdx.x & 63;                        // 0..63
  int j = d & 31;
  float invf = __expf((float)j * (-13.815510558f / 32.f));
  float sn, cs;
  sincosf((float)pos[t * 3 + (j % 3)] * invf, &sn, &cs);
  const short* base = qkvb + (size_t)bt * 1280;
  float wq = qw[d], wk = kw[d];

  auto rowproc = [&](float x, float w) -> float {
    float ss = x * x;
    ss += __shfl_xor(ss, 1);  ss += __shfl_xor(ss, 2);  ss += __shfl_xor(ss, 4);
    ss += __shfl_xor(ss, 8);  ss += __shfl_xor(ss, 16); ss += __shfl_xor(ss, 32);
    float xn = x * rsqrtf(ss * 0.015625f + 1e-6f) * w;
    float pr = __shfl_xor(xn, 32);                 // RoPE partner d +- 32
    return (d < 32) ? xn * cs - pr * sn : xn * cs + pr * sn;
  };
  {
    float x = bf2f((unsigned short)base[1024 + d]);
    kb[(size_t)bt * 64 + d] = (short)f2bf(rowproc(x, wk));
  }
#pragma unroll 4
  for (int hh = 0; hh < 16; ++hh) {
    float x = bf2f((unsigned short)base[hh * 64 + d]);
    qb[((size_t)((b * 16 + hh) * 4096 + t)) * 64 + d] = (short)f2bf(rowproc(x, wq));
  }
}

// ---------------- kernel: V slice of qkv -> vtg[b][64][4096] ----------------
__global__ __launch_bounds__(256) void k_vt(const short* __restrict__ qkvb,
                                            short* __restrict__ vtg) {
  __shared__ short ts[64][72];                     // 72: 16B-aligned rows
  int t0 = blockIdx.x * 64;
  int b = t0 >> 12, tl0 = t0 & 4095;
  int row = threadIdx.x >> 2, c4 = threadIdx.x & 3;
  const short* src = qkvb + (size_t)(t0 + row) * 1280 + 1088 + c4 * 16;
  *(short8*)&ts[row][c4 * 16]     = *(const short8*)src;
  *(short8*)&ts[row][c4 * 16 + 8] = *(const short8*)(src + 8);
  __syncthreads();
  short8 o0, o1;                                   // row = d, c4 = token group
#pragma unroll
  for (int jj = 0; jj < 8; ++jj) {
    o0[jj] = ts[c4 * 16 + jj][row];
    o1[jj] = ts[c4 * 16 + 8 + jj][row];
  }
  short* dst = vtg + (size_t)(b * 64 + row) * 4096 + tl0 + c4 * 16;
  *(short8*)dst = o0;
  *(short8*)(dst + 8) = o1;
}

// ---------------- kernel: blocked sliding-window attention (swapped QK^T) ----
// grid 2048 = (b, n, h fastest). 4 waves x 32 q-rows. Per-32-key-subtile
// online softmax keeps only one f32x16 S live -> no VGPR spill at 128-reg cap.
__global__ __launch_bounds__(256, 4) void k_attn(const short* __restrict__ qb,
                                                 const short* __restrict__ kb,
                                                 const short* __restrict__ vtg,
                                                 short* __restrict__ y) {
  __shared__ __align__(16) char smem[33792];
  short* ks  = (short*)smem;            // [128 key][64 d], chunk-XOR swizzled
  short* vts = (short*)(smem + 16384);  // [64 d][128 key], chunk-XOR swizzled
  int bid = blockIdx.x;
  int swz = (bid & 7) * 256 + (bid >> 3);          // XCD swizzle
  int h = swz & 15, n = (swz >> 4) & 31, b = swz >> 9;
  int tid = threadIdx.x, wid = tid >> 6, lane = tid & 63;
  int lo = lane & 31, hi = lane >> 5;

  // Q fragments (B-operand: col = q-row = lane&31, k-chunk = s*16 + hi*8)
  const short* qrow = qb + (size_t)((b * 16 + h) * 4096 + n * 128 + wid * 32 + lo) * 64;
  short8 aq[4];
#pragma unroll
  for (int s = 0; s < 4; ++s) aq[s] = *(const short8*)(qrow + s * 16 + hi * 8);

  f32x16 O0 = {}, O1 = {};                         // O^T: rows d / d+32, col q
  float mrun = -1e30f, lrun = 0.f;
  int qr = wid * 32 + lo;
  const float SC = 0.125f * 1.4426950408889634f;   // scale * log2(e)

  for (int hf = (n == 0) ? 1 : 0; hf < 2; ++hf) {  // n==0: half0 fully masked
    int tg = (n - 1 + hf) * 128;                   // first key token (within b)
    // stage K: LDS slot (r, dc) <- global chunk dc^(r&7)  (linear DMA dest)
#pragma unroll
    for (int p = 0; p < 4; ++p) {
      int idx = p * 256 + tid;
      int r = idx >> 3, dc = idx & 7;
      gload16(kb + (size_t)(b * 4096 + tg + r) * 64 + ((dc ^ (r & 7)) << 3),
              ks + idx * 8);
    }
    // stage V^T: LDS slot (dd, s) <- global key-chunk s^(dd&7)
#pragma unroll
    for (int p = 0; p < 4; ++p) {
      int idx = p * 256 + tid;
      int dd = idx >> 4, s = idx & 15;
      gload16(vtg + (size_t)(b * 64 + dd) * 4096 + tg + ((s ^ (dd & 7)) << 3),
              vts + idx * 8);
    }
    __syncthreads();

#pragma unroll
    for (int mt = 0; mt < 4; ++mt) {
      // S^T subtile = K(32 keys) * Q^T : one f32x16 live at a time
      f32x16 S = {};
      int r = mt * 32 + lo;
#pragma unroll
      for (int kst = 0; kst < 4; ++kst) {
        short8 kf = *(const short8*)&ks[r * 64 + ((((kst << 1) | hi) ^ (r & 7)) << 3)];
        S = mfma32(kf, aq[kst], S);
      }
      // mask + scale into log2 domain: key = 32*mt + (reg&3)+8*(reg>>2)+4*hi
#pragma unroll
      for (int rr = 0; rr < 16; ++rr) {
        int kg = hf * 128 + mt * 32 + (rr & 3) + ((rr >> 2) << 3) + (hi << 2);
        S[rr] = (kg >= qr && kg <= qr + 128) ? S[rr] * SC : -30000.f;
      }
      // online max with defer-rescale (T13): skip O-rescale if growth <= 8
      float pmax = S[0];
#pragma unroll
      for (int rr = 1; rr < 16; ++rr) pmax = fmaxf(pmax, S[rr]);
      pmax = fmaxf(pmax, __shfl_xor(pmax, 32));
      if (!__all(pmax - mrun <= 8.f)) {
        float mn = fmaxf(mrun, pmax);
        float al = exp2f(mrun - mn);
        lrun *= al; mrun = mn;
#pragma unroll
        for (int rr = 0; rr < 16; ++rr) { O0[rr] *= al; O1[rr] *= al; }
      }
      float ls = 0.f;
#pragma unroll
      for (int rr = 0; rr < 16; ++rr) { S[rr] = exp2f(S[rr] - mrun); ls += S[rr]; }
      ls += __shfl_xor(ls, 32);
      lrun += ls;
      // O^T += V^T * P : pack P^T B-fragments via cvt_pk + permlane32_swap
#pragma unroll
      for (int h2 = 0; h2 < 2; ++h2) {
        int b0 = h2 * 8;
        unsigned pk0 = cvtpk(S[b0 + 0], S[b0 + 1]);
        unsigned pk1 = cvtpk(S[b0 + 2], S[b0 + 3]);
        unsigned pk2 = cvtpk(S[b0 + 4], S[b0 + 5]);
        unsigned pk3 = cvtpk(S[b0 + 6], S[b0 + 7]);
        asm("v_permlane32_swap_b32 %0, %1" : "+v"(pk0), "+v"(pk2));
        asm("v_permlane32_swap_b32 %0, %1" : "+v"(pk1), "+v"(pk3));
        uint4v uw; uw.x = pk0; uw.y = pk1; uw.z = pk2; uw.w = pk3;
        short8 pb = __builtin_bit_cast(short8, uw);
        int kc = mt * 4 + h2 * 2 + hi;             // key chunk 0..15
        short8 vb0 = *(const short8*)&vts[lo * 128 + ((kc ^ (lo & 7)) << 3)];
        short8 vb1 = *(const short8*)&vts[(32 + lo) * 128 + ((kc ^ (lo & 7)) << 3)];
        O0 = mfma32(vb0, pb, O0);
        O1 = mfma32(vb1, pb, O1);
      }
    }
    __syncthreads();
  }

  // epilogue: O^T/l -> LDS transpose -> coalesced bf16 stores
  float inv = 1.f / lrun;
  float* ot = (float*)smem + wid * 2112;           // [64 d][33] per wave
#pragma unroll
  for (int r = 0; r < 16; ++r) {
    int d0 = (r & 3) + ((r >> 2) << 3) + (hi << 2);
    ot[d0 * 33 + lo]        = O0[r] * inv;
    ot[(d0 + 32) * 33 + lo] = O1[r] * inv;
  }
  __syncthreads();
  int tok = lane >> 3, dc = lane & 7;
#pragma unroll
  for (int g = 0; g < 4; ++g) {
    int q = g * 8 + tok;
    short8 o8;
#pragma unroll
    for (int jj = 0; jj < 8; ++jj)
      o8[jj] = (short)f2bf(ot[(dc * 8 + jj) * 33 + q]);
    *(short8*)&y[(size_t)(b * 4096 + n * 128 + wid * 32 + q) * 1024 + h * 64 + dc * 8] = o8;
  }
}

// ---------------- launch ----------------
extern "C" void kernel_launch(void* const* d_in, const int* in_sizes, int n_in,
                              void* d_out, int out_size, void* d_ws, size_t ws_size,
                              hipStream_t stream) {
  const float* x      = (const float*)d_in[0];
  const int*   pos    = (const int*)d_in[1];
  const float* w_attn = (const float*)d_in[2];
  const float* w_proj = (const float*)d_in[3];
  const float* qw     = (const float*)d_in[4];
  const float* kw     = (const float*)d_in[5];

  char* ws = (char*)d_ws;
  short* xb   = (short*)ws;                         // 33,554,432 B (aliased as y later)
  short* wabt = (short*)(ws + 33554432);            //  2,621,440 B (1280 x 1024)
  short* wpbt = (short*)(ws + 36175872);            //  2,097,152 B
  short* qkvb = (short*)(ws + 38273024);            // 41,943,040 B (16384 x 1280)
  short* qb2  = (short*)(ws + 80216064);            // 33,554,432 B
  short* kb2  = (short*)(ws + 113770496);           //  2,097,152 B
  short* vtg  = (short*)(ws + 115867648);           //  2,097,152 B (total 112.5 MiB)
  short* ybuf = xb;                                 // xb dead after qkv GEMM

  hipLaunchKernelGGL(k_cvt, dim3(16384), dim3(256), 0, stream, x, xb, 4194304);
  hipLaunchKernelGGL(k_tcvt, dim3(32, 36), dim3(256), 0, stream, w_attn, wabt, 1024, 1152);
  hipLaunchKernelGGL(k_tcvt, dim3(32, 32), dim3(256), 0, stream, w_proj, wpbt, 1024, 1024);
  hipLaunchKernelGGL(k_gemm256, dim3(320), dim3(512), 0, stream, xb, wabt, (void*)qkvb,
                     16384, 1280, 1024, 1);
  hipLaunchKernelGGL(k_qk, dim3(4096), dim3(256), 0, stream, qkvb, pos, qw, kw, qb2, kb2);
  hipLaunchKernelGGL(k_vt, dim3(256), dim3(256), 0, stream, qkvb, vtg);
  hipLaunchKernelGGL(k_attn, dim3(2048), dim3(256), 0, stream, qb2, kb2, vtg, ybuf);
  hipLaunchKernelGGL(k_gemm256, dim3(256), dim3(512), 0, stream, ybuf, wpbt, d_out,
                     16384, 1024, 1024, 0);
}

// Round 7
// 175.682 us; speedup vs baseline: 1.1272x; 1.1272x over previous
//
#include <hip/hip_runtime.h>

// MQA fused layer, MI355X gfx950.
// B=4 T=4096 C=1024 H=16 D=64 W=128 NB=32.
// Pipeline: cvt(x)->bf16 | transpose-cvt weights | trig table | GEMM qkv
//           (256^2, fused RMS+RoPE+transpose epilogue -> qb2/kb2/vtg) |
//           blocked sliding-window attention | GEMM proj (256^2) -> d_out.

typedef __attribute__((ext_vector_type(8))) short short8;
typedef __attribute__((ext_vector_type(4))) float f32x4;
typedef __attribute__((ext_vector_type(16))) float f32x16;
typedef __attribute__((ext_vector_type(4))) unsigned uint4v;

#define DEV static __device__ __forceinline__

DEV unsigned short f2bf(float f) {           // fp32 -> bf16 RNE
  unsigned u = __builtin_bit_cast(unsigned, f);
  u += 0x7fffu + ((u >> 16) & 1u);
  return (unsigned short)(u >> 16);
}
DEV float bf2f(unsigned short s) {
  unsigned u = ((unsigned)s) << 16;
  return __builtin_bit_cast(float, u);
}
DEV unsigned cvtpk(float a, float b) {       // {bf16(a), bf16(b)} packed
  unsigned r;
  asm("v_cvt_pk_bf16_f32 %0, %1, %2" : "=v"(r) : "v"(a), "v"(b));
  return r;
}

DEV f32x4 mfma16(short8 a, short8 b, f32x4 c) {
  return __builtin_amdgcn_mfma_f32_16x16x32_bf16(a, b, c, 0, 0, 0);
}
DEV f32x16 mfma32(short8 a, short8 b, f32x16 c) {
  return __builtin_amdgcn_mfma_f32_32x32x16_bf16(a, b, c, 0, 0, 0);
}

// async global->LDS, 16B per lane
DEV void gload16(const void* g, void* l) {
  __builtin_amdgcn_global_load_lds(
      (const __attribute__((address_space(1))) unsigned int*)(unsigned long long)g,
      (__attribute__((address_space(3))) unsigned int*)(unsigned int)(unsigned long long)l,
      16, 0, 0);
}

#define BARRIER __builtin_amdgcn_s_barrier()
#define LGKM0  asm volatile("s_waitcnt lgkmcnt(0)" ::: "memory")
#define VMCNT4 asm volatile("s_waitcnt vmcnt(4)" ::: "memory")

// ---------------- kernel: f32 -> bf16 elementwise ----------------
__global__ __launch_bounds__(256) void k_cvt(const float* __restrict__ in,
                                             short* __restrict__ out, int n4) {
  int i = blockIdx.x * 256 + threadIdx.x;
  if (i >= n4) return;
  float4 v = ((const float4*)in)[i];
  short4 o;
  o.x = (short)f2bf(v.x); o.y = (short)f2bf(v.y);
  o.z = (short)f2bf(v.z); o.w = (short)f2bf(v.w);
  ((short4*)out)[i] = o;
}

// ---------------- kernel: W (KxN f32) -> Wt (NxK bf16) ----------------
__global__ __launch_bounds__(256) void k_tcvt(const float* __restrict__ W,
                                              short* __restrict__ Wt, int K, int N) {
  __shared__ float tl[32][33];
  int tx = threadIdx.x & 31, ty = threadIdx.x >> 5;   // 32 x 8
  int k0 = blockIdx.x * 32, n0 = blockIdx.y * 32;
#pragma unroll
  for (int i = 0; i < 4; ++i)
    tl[ty + i * 8][tx] = W[(size_t)(k0 + ty + i * 8) * N + n0 + tx];
  __syncthreads();
#pragma unroll
  for (int i = 0; i < 4; ++i)
    Wt[(size_t)(n0 + ty + i * 8) * K + k0 + tx] = (short)f2bf(tl[tx][ty + i * 8]);
}

// ---------------- kernel: RoPE cos/sin table [4096][32] ----------------
__global__ __launch_bounds__(256) void k_trig(const int* __restrict__ pos,
                                              float* __restrict__ ct,
                                              float* __restrict__ st) {
  int idx = blockIdx.x * 256 + threadIdx.x;          // 131072 = 4096*32
  int t = idx >> 5, j = idx & 31;
  float invf = __expf((float)j * (-13.815510558f / 32.f));
  float p = (float)pos[t * 3 + (j % 3)];
  float s, c;
  sincosf(p * invf, &s, &c);
  ct[idx] = c;
  st[idx] = s;
}

// ---------------- kernel: 256x256x64 bf16 GEMM, 8-phase schedule ------------
// mode 0: plain C write (f32/bf16). mode 1 (qkv): fused epilogue — per-wave
// 128x64 acc block = one 64-wide head slice; RMS+RoPE in-register (partner
// d+-32 = acc[m][nf^2][r], same lane), LDS transpose, write qb2/kb2/vtg.
__global__ __launch_bounds__(512, 2) void k_gemm256(
    const short* __restrict__ A, const short* __restrict__ Bt,
    void* __restrict__ Cout, int M, int N, int K, int outBf16,
    const float* __restrict__ ct, const float* __restrict__ st,
    const float* __restrict__ qw, const float* __restrict__ kw,
    short* __restrict__ qb2, short* __restrict__ kb2, short* __restrict__ vtg,
    int mode) {
  __shared__ short sm[65536];                       // 128 KiB
  int nbn = N >> 8;
  int nwg = (M >> 8) * nbn;
  int bid = blockIdx.x;
  int swz = (bid & 7) * (nwg >> 3) + (bid >> 3);    // XCD swizzle (nwg % 8 == 0)
  int bm = swz / nbn, bn = swz % nbn;
  int tid = threadIdx.x, wid = tid >> 6, lane = tid & 63;
  int wm = wid >> 2, wn = wid & 3;
  int lo = lane & 15, hi = lane >> 4;
  int NT = K >> 6;                                  // # K-tiles (BK=64)

  // staging: thread covers (row r0, chunk dc) and (r0+64, dc) of a 128x8-chunk half
  int r0 = tid >> 3, dc = tid & 7;
  int sc = dc ^ (r0 & 7);                           // pre-swizzled source chunk
  const short* aS0 = A  + (size_t)(bm * 256 + r0) * K + sc * 8;        // half 0
  const short* bS0 = Bt + (size_t)(bn * 256 + r0) * K + sc * 8;
  size_t hstep = (size_t)128 * K;                   // half 1 = +128 rows

  auto stage = [&](int jt, int mat, int h, int d) {
    const short* s = (mat ? bS0 : aS0) + (size_t)h * hstep + jt * 64;
    short* l = sm + d * 32768 + mat * 16384 + h * 8192;
    gload16(s,                     l + tid * 8);
    gload16(s + (size_t)64 * K,    l + 4096 + tid * 8);
  };

  int aRd[2];
#pragma unroll
  for (int kk = 0; kk < 2; ++kk)
    aRd[kk] = lo * 64 + (((kk << 2) | hi) ^ (lo & 7)) * 8;

  short8 Afr[8][2];
  short8 Bfr[2][2];
  f32x4 acc[8][4] = {};

  auto rdA = [&](int d, int m0) {
    int base = d * 32768 + wm * 8192;
#pragma unroll
    for (int m = 0; m < 4; ++m)
#pragma unroll
      for (int kk = 0; kk < 2; ++kk)
        Afr[m0 + m][kk] = *(const short8*)&sm[base + (m0 + m) * 1024 + aRd[kk]];
  };
  auto rdB = [&](int d, int n0) {
    int base = d * 32768 + 16384 + (wn >> 1) * 8192 + (wn & 1) * 4096;
#pragma unroll
    for (int nf = 0; nf < 2; ++nf)
#pragma unroll
      for (int kk = 0; kk < 2; ++kk)
        Bfr[nf][kk] = *(const short8*)&sm[base + (n0 + nf) * 1024 + aRd[kk]];
  };
  auto quad = [&](int m0, int n0) {
    __builtin_amdgcn_s_setprio(1);
#pragma unroll
    for (int m = 0; m < 4; ++m)
#pragma unroll
      for (int j = 0; j < 2; ++j)
#pragma unroll
        for (int kk = 0; kk < 2; ++kk)
          acc[m0 + m][n0 + j] = mfma16(Afr[m0 + m][kk], Bfr[j][kk], acc[m0 + m][n0 + j]);
    __builtin_amdgcn_s_setprio(0);
  };

  stage(0, 0, 0, 0); stage(0, 1, 0, 0); stage(0, 0, 1, 0); stage(0, 1, 1, 0);
  if (NT > 1) { stage(1, 0, 0, 1); stage(1, 1, 0, 1); }
  VMCNT4;
  BARRIER;

#pragma unroll 2
  for (int jt = 0; jt < NT; ++jt) {
    int d = jt & 1;
    rdA(d, 0); rdB(d, 0);
    if (jt + 1 < NT) stage(jt + 1, 0, 1, d ^ 1);
    BARRIER; LGKM0;
    quad(0, 0);
    BARRIER;
    rdA(d, 4);
    if (jt + 1 < NT) stage(jt + 1, 1, 1, d ^ 1);
    BARRIER; LGKM0;
    quad(4, 0);
    BARRIER;
    rdB(d, 2);
    if (jt + 2 < NT) stage(jt + 2, 0, 0, d);
    BARRIER; LGKM0;
    quad(0, 2);
    BARRIER;
    if (jt + 2 < NT) stage(jt + 2, 1, 0, d);
    VMCNT4;
    BARRIER;
    quad(4, 2);
    BARRIER;
  }

  if (mode == 1) {
    // ---- fused qkv epilogue: RMS+RoPE (Q,K), passthrough (V), LDS transpose
    int tg0 = (bm * 256 + wm * 128) & 4095;          // token base (within batch)
    int bb  = (bm * 256) >> 12;                      // batch index
    bool isQ = bn < 4, isK = (bn == 4 && wn == 0), isV = (bn == 4 && wn == 1);
    short* smw = sm + wid * 8192;                    // per-wave 16 KB scratch
    if (isQ || isK) {
      const float* nw = isQ ? qw : kw;
      float w0 = nw[lo], w1 = nw[16 + lo], w2 = nw[32 + lo], w3 = nw[48 + lo];
#pragma unroll
      for (int m = 0; m < 8; ++m)
#pragma unroll
        for (int r = 0; r < 4; ++r) {
          float x0 = acc[m][0][r], x1 = acc[m][1][r];
          float x2 = acc[m][2][r], x3 = acc[m][3][r];
          float ss = x0 * x0 + x1 * x1 + x2 * x2 + x3 * x3;
          ss += __shfl_xor(ss, 1); ss += __shfl_xor(ss, 2);
          ss += __shfl_xor(ss, 4); ss += __shfl_xor(ss, 8);
          float rn = rsqrtf(ss * 0.015625f + 1e-6f);
          x0 *= rn * w0; x1 *= rn * w1; x2 *= rn * w2; x3 *= rn * w3;
          int tp = m * 16 + hi * 4 + r;              // wave-local row 0..127
          int tloc = tg0 + tp;
          float c0 = ct[tloc * 32 + lo],      s0 = st[tloc * 32 + lo];
          float c1 = ct[tloc * 32 + 16 + lo], s1 = st[tloc * 32 + 16 + lo];
          float o0 = x0 * c0 - x2 * s0;              // d = lo
          float o1 = x1 * c1 - x3 * s1;              // d = 16+lo
          float o2 = x2 * c0 + x0 * s0;              // d = 32+lo
          float o3 = x3 * c1 + x1 * s1;              // d = 48+lo
          smw[tp * 64 + lo]      = (short)f2bf(o0);
          smw[tp * 64 + 16 + lo] = (short)f2bf(o1);
          smw[tp * 64 + 32 + lo] = (short)f2bf(o2);
          smw[tp * 64 + 48 + lo] = (short)f2bf(o3);
        }
    } else if (isV) {
#pragma unroll
      for (int m = 0; m < 8; ++m)
#pragma unroll
        for (int nf = 0; nf < 4; ++nf)
#pragma unroll
          for (int r = 0; r < 4; ++r)                // [d][t'] orientation
            smw[(nf * 16 + lo) * 128 + m * 16 + hi * 4 + r] =
                (short)f2bf(acc[m][nf][r]);
    }
    __syncthreads();
    if (isQ) {
      int hh = bn * 4 + wn;
      short* dst = qb2 + (size_t)(bb * 16 + hh) * 4096 * 64;
#pragma unroll
      for (int i = 0; i < 16; ++i) {
        int c = i * 64 + lane, tp = c >> 3, d2 = c & 7;
        *(short8*)&dst[(size_t)(tg0 + tp) * 64 + d2 * 8] =
            *(const short8*)&smw[tp * 64 + d2 * 8];
      }
    } else if (isK) {
#pragma unroll
      for (int i = 0; i < 16; ++i) {
        int c = i * 64 + lane, tp = c >> 3, d2 = c & 7;
        *(short8*)&kb2[((size_t)bb * 4096 + tg0 + tp) * 64 + d2 * 8] =
            *(const short8*)&smw[tp * 64 + d2 * 8];
      }
    } else if (isV) {
#pragma unroll
      for (int i = 0; i < 16; ++i) {
        int c = i * 64 + lane, dd = c >> 4, tc = c & 15;
        *(short8*)&vtg[((size_t)(bb * 64 + dd)) * 4096 + tg0 + tc * 8] =
            *(const short8*)&smw[dd * 128 + tc * 8];
      }
    }
    return;
  }

  // ---- mode 0: plain C write. layout col = lane&15, row = (lane>>4)*4 + reg
  int row0 = bm * 256 + wm * 128 + hi * 4;
  int col0 = bn * 256 + wn * 64 + lo;
  if (outBf16) {
    short* C = (short*)Cout;
#pragma unroll
    for (int m = 0; m < 8; ++m)
#pragma unroll
      for (int nf = 0; nf < 4; ++nf)
#pragma unroll
        for (int r = 0; r < 4; ++r)
          C[(size_t)(row0 + m * 16 + r) * N + col0 + nf * 16] = (short)f2bf(acc[m][nf][r]);
  } else {
    float* C = (float*)Cout;
#pragma unroll
    for (int m = 0; m < 8; ++m)
#pragma unroll
      for (int nf = 0; nf < 4; ++nf)
#pragma unroll
        for (int r = 0; r < 4; ++r)
          C[(size_t)(row0 + m * 16 + r) * N + col0 + nf * 16] = acc[m][nf][r];
  }
}

// ---------------- kernel: blocked sliding-window attention (swapped QK^T) ----
// grid 2048 = (b, n, h fastest). 4 waves x 32 q-rows. Per-32-key-subtile
// online softmax keeps only one f32x16 S live -> no VGPR spill at 128-reg cap.
__global__ __launch_bounds__(256, 4) void k_attn(const short* __restrict__ qb,
                                                 const short* __restrict__ kb,
                                                 const short* __restrict__ vtg,
                                                 short* __restrict__ y) {
  __shared__ __align__(16) char smem[33792];
  short* ks  = (short*)smem;            // [128 key][64 d], chunk-XOR swizzled
  short* vts = (short*)(smem + 16384);  // [64 d][128 key], chunk-XOR swizzled
  int bid = blockIdx.x;
  int swz = (bid & 7) * 256 + (bid >> 3);          // XCD swizzle
  int h = swz & 15, n = (swz >> 4) & 31, b = swz >> 9;
  int tid = threadIdx.x, wid = tid >> 6, lane = tid & 63;
  int lo = lane & 31, hi = lane >> 5;

  const short* qrow = qb + (size_t)((b * 16 + h) * 4096 + n * 128 + wid * 32 + lo) * 64;
  short8 aq[4];
#pragma unroll
  for (int s = 0; s < 4; ++s) aq[s] = *(const short8*)(qrow + s * 16 + hi * 8);

  f32x16 O0 = {}, O1 = {};                         // O^T: rows d / d+32, col q
  float mrun = -1e30f, lrun = 0.f;
  int qr = wid * 32 + lo;
  const float SC = 0.125f * 1.4426950408889634f;   // scale * log2(e)

  for (int hf = (n == 0) ? 1 : 0; hf < 2; ++hf) {  // n==0: half0 fully masked
    int tg = (n - 1 + hf) * 128;                   // first key token (within b)
#pragma unroll
    for (int p = 0; p < 4; ++p) {
      int idx = p * 256 + tid;
      int r = idx >> 3, dc = idx & 7;
      gload16(kb + (size_t)(b * 4096 + tg + r) * 64 + ((dc ^ (r & 7)) << 3),
              ks + idx * 8);
    }
#pragma unroll
    for (int p = 0; p < 4; ++p) {
      int idx = p * 256 + tid;
      int dd = idx >> 4, s = idx & 15;
      gload16(vtg + (size_t)(b * 64 + dd) * 4096 + tg + ((s ^ (dd & 7)) << 3),
              vts + idx * 8);
    }
    __syncthreads();

#pragma unroll
    for (int mt = 0; mt < 4; ++mt) {
      f32x16 S = {};
      int r = mt * 32 + lo;
#pragma unroll
      for (int kst = 0; kst < 4; ++kst) {
        short8 kf = *(const short8*)&ks[r * 64 + ((((kst << 1) | hi) ^ (r & 7)) << 3)];
        S = mfma32(kf, aq[kst], S);
      }
#pragma unroll
      for (int rr = 0; rr < 16; ++rr) {
        int kg = hf * 128 + mt * 32 + (rr & 3) + ((rr >> 2) << 3) + (hi << 2);
        S[rr] = (kg >= qr && kg <= qr + 128) ? S[rr] * SC : -30000.f;
      }
      float pmax = S[0];
#pragma unroll
      for (int rr = 1; rr < 16; ++rr) pmax = fmaxf(pmax, S[rr]);
      pmax = fmaxf(pmax, __shfl_xor(pmax, 32));
      if (!__all(pmax - mrun <= 8.f)) {
        float mn = fmaxf(mrun, pmax);
        float al = exp2f(mrun - mn);
        lrun *= al; mrun = mn;
#pragma unroll
        for (int rr = 0; rr < 16; ++rr) { O0[rr] *= al; O1[rr] *= al; }
      }
      float ls = 0.f;
#pragma unroll
      for (int rr = 0; rr < 16; ++rr) { S[rr] = exp2f(S[rr] - mrun); ls += S[rr]; }
      ls += __shfl_xor(ls, 32);
      lrun += ls;
#pragma unroll
      for (int h2 = 0; h2 < 2; ++h2) {
        int b0 = h2 * 8;
        unsigned pk0 = cvtpk(S[b0 + 0], S[b0 + 1]);
        unsigned pk1 = cvtpk(S[b0 + 2], S[b0 + 3]);
        unsigned pk2 = cvtpk(S[b0 + 4], S[b0 + 5]);
        unsigned pk3 = cvtpk(S[b0 + 6], S[b0 + 7]);
        asm("v_permlane32_swap_b32 %0, %1" : "+v"(pk0), "+v"(pk2));
        asm("v_permlane32_swap_b32 %0, %1" : "+v"(pk1), "+v"(pk3));
        uint4v uw; uw.x = pk0; uw.y = pk1; uw.z = pk2; uw.w = pk3;
        short8 pb = __builtin_bit_cast(short8, uw);
        int kc = mt * 4 + h2 * 2 + hi;
        short8 vb0 = *(const short8*)&vts[lo * 128 + ((kc ^ (lo & 7)) << 3)];
        short8 vb1 = *(const short8*)&vts[(32 + lo) * 128 + ((kc ^ (lo & 7)) << 3)];
        O0 = mfma32(vb0, pb, O0);
        O1 = mfma32(vb1, pb, O1);
      }
    }
    __syncthreads();
  }

  float inv = 1.f / lrun;
  float* ot = (float*)smem + wid * 2112;           // [64 d][33] per wave
#pragma unroll
  for (int r = 0; r < 16; ++r) {
    int d0 = (r & 3) + ((r >> 2) << 3) + (hi << 2);
    ot[d0 * 33 + lo]        = O0[r] * inv;
    ot[(d0 + 32) * 33 + lo] = O1[r] * inv;
  }
  __syncthreads();
  int tok = lane >> 3, dc = lane & 7;
#pragma unroll
  for (int g = 0; g < 4; ++g) {
    int q = g * 8 + tok;
    short8 o8;
#pragma unroll
    for (int jj = 0; jj < 8; ++jj)
      o8[jj] = (short)f2bf(ot[(dc * 8 + jj) * 33 + q]);
    *(short8*)&y[(size_t)(b * 4096 + n * 128 + wid * 32 + q) * 1024 + h * 64 + dc * 8] = o8;
  }
}

// ---------------- launch ----------------
extern "C" void kernel_launch(void* const* d_in, const int* in_sizes, int n_in,
                              void* d_out, int out_size, void* d_ws, size_t ws_size,
                              hipStream_t stream) {
  const float* x      = (const float*)d_in[0];
  const int*   pos    = (const int*)d_in[1];
  const float* w_attn = (const float*)d_in[2];
  const float* w_proj = (const float*)d_in[3];
  const float* qw     = (const float*)d_in[4];
  const float* kw     = (const float*)d_in[5];

  char* ws = (char*)d_ws;
  short* xb   = (short*)ws;                         // 33,554,432 B (aliased as y later)
  short* wabt = (short*)(ws + 33554432);            //  2,621,440 B (1280 x 1024, pad rows untouched)
  short* wpbt = (short*)(ws + 36175872);            //  2,097,152 B
  short* qb2  = (short*)(ws + 38273024);            // 33,554,432 B
  short* kb2  = (short*)(ws + 71827456);            //  2,097,152 B
  short* vtg  = (short*)(ws + 73924608);            //  2,097,152 B
  float* ctab = (float*)(ws + 76021760);            //    524,288 B
  float* stab = (float*)(ws + 76546048);            //    524,288 B (total ~73.5 MiB)
  short* ybuf = xb;                                 // xb dead after qkv GEMM

  hipLaunchKernelGGL(k_cvt, dim3(16384), dim3(256), 0, stream, x, xb, 4194304);
  hipLaunchKernelGGL(k_tcvt, dim3(32, 36), dim3(256), 0, stream, w_attn, wabt, 1024, 1152);
  hipLaunchKernelGGL(k_tcvt, dim3(32, 32), dim3(256), 0, stream, w_proj, wpbt, 1024, 1024);
  hipLaunchKernelGGL(k_trig, dim3(512), dim3(256), 0, stream, pos, ctab, stab);
  hipLaunchKernelGGL(k_gemm256, dim3(320), dim3(512), 0, stream, xb, wabt,
                     (void*)nullptr, 16384, 1280, 1024, 1,
                     ctab, stab, qw, kw, qb2, kb2, vtg, 1);
  hipLaunchKernelGGL(k_attn, dim3(2048), dim3(256), 0, stream, qb2, kb2, vtg, ybuf);
  hipLaunchKernelGGL(k_gemm256, dim3(256), dim3(512), 0, stream, ybuf, wpbt, d_out,
                     16384, 1024, 1024, 0,
                     (const float*)nullptr, (const float*)nullptr,
                     (const float*)nullptr, (const float*)nullptr,
                     (short*)nullptr, (short*)nullptr, (short*)nullptr, 0);
}

// Round 8
// 175.526 us; speedup vs baseline: 1.1282x; 1.0009x over previous
//
#include <hip/hip_runtime.h>

// MQA fused layer, MI355X gfx950.
// B=4 T=4096 C=1024 H=16 D=64 W=128 NB=32.
// Pipeline: cvt(x)->bf16 | transpose-cvt weights | trig table | GEMM qkv
//           (256^2, fused RMS+RoPE epilogue, direct global stores ->
//           qb2/kb2/vtg) | blocked sliding-window attention | GEMM proj.

typedef __attribute__((ext_vector_type(8))) short short8;
typedef __attribute__((ext_vector_type(4))) float f32x4;
typedef __attribute__((ext_vector_type(16))) float f32x16;
typedef __attribute__((ext_vector_type(4))) unsigned uint4v;

#define DEV static __device__ __forceinline__

DEV unsigned short f2bf(float f) {           // fp32 -> bf16 RNE
  unsigned u = __builtin_bit_cast(unsigned, f);
  u += 0x7fffu + ((u >> 16) & 1u);
  return (unsigned short)(u >> 16);
}
DEV float bf2f(unsigned short s) {
  unsigned u = ((unsigned)s) << 16;
  return __builtin_bit_cast(float, u);
}
DEV unsigned cvtpk(float a, float b) {       // {bf16(a), bf16(b)} packed
  unsigned r;
  asm("v_cvt_pk_bf16_f32 %0, %1, %2" : "=v"(r) : "v"(a), "v"(b));
  return r;
}

DEV f32x4 mfma16(short8 a, short8 b, f32x4 c) {
  return __builtin_amdgcn_mfma_f32_16x16x32_bf16(a, b, c, 0, 0, 0);
}
DEV f32x16 mfma32(short8 a, short8 b, f32x16 c) {
  return __builtin_amdgcn_mfma_f32_32x32x16_bf16(a, b, c, 0, 0, 0);
}

// async global->LDS, 16B per lane
DEV void gload16(const void* g, void* l) {
  __builtin_amdgcn_global_load_lds(
      (const __attribute__((address_space(1))) unsigned int*)(unsigned long long)g,
      (__attribute__((address_space(3))) unsigned int*)(unsigned int)(unsigned long long)l,
      16, 0, 0);
}

#define BARRIER __builtin_amdgcn_s_barrier()
#define LGKM0  asm volatile("s_waitcnt lgkmcnt(0)" ::: "memory")
#define VMCNT4 asm volatile("s_waitcnt vmcnt(4)" ::: "memory")

// ---------------- kernel: f32 -> bf16 elementwise ----------------
__global__ __launch_bounds__(256) void k_cvt(const float* __restrict__ in,
                                             short* __restrict__ out, int n4) {
  int i = blockIdx.x * 256 + threadIdx.x;
  if (i >= n4) return;
  float4 v = ((const float4*)in)[i];
  short4 o;
  o.x = (short)f2bf(v.x); o.y = (short)f2bf(v.y);
  o.z = (short)f2bf(v.z); o.w = (short)f2bf(v.w);
  ((short4*)out)[i] = o;
}

// ---------------- kernel: W (KxN f32) -> Wt (NxK bf16) ----------------
__global__ __launch_bounds__(256) void k_tcvt(const float* __restrict__ W,
                                              short* __restrict__ Wt, int K, int N) {
  __shared__ float tl[32][33];
  int tx = threadIdx.x & 31, ty = threadIdx.x >> 5;   // 32 x 8
  int k0 = blockIdx.x * 32, n0 = blockIdx.y * 32;
#pragma unroll
  for (int i = 0; i < 4; ++i)
    tl[ty + i * 8][tx] = W[(size_t)(k0 + ty + i * 8) * N + n0 + tx];
  __syncthreads();
#pragma unroll
  for (int i = 0; i < 4; ++i)
    Wt[(size_t)(n0 + ty + i * 8) * K + k0 + tx] = (short)f2bf(tl[tx][ty + i * 8]);
}

// ---------------- kernel: RoPE (cos,sin) interleaved table [4096][32] --------
__global__ __launch_bounds__(256) void k_trig(const int* __restrict__ pos,
                                              float* __restrict__ tbl) {
  int idx = blockIdx.x * 256 + threadIdx.x;          // 131072 = 4096*32
  int t = idx >> 5, j = idx & 31;
  float invf = __expf((float)j * (-13.815510558f / 32.f));
  float p = (float)pos[t * 3 + (j % 3)];
  float s, c;
  sincosf(p * invf, &s, &c);
  ((float2*)tbl)[idx] = make_float2(c, s);
}

// ---------------- kernel: 256x256x64 bf16 GEMM, 8-phase schedule ------------
// mode 0: plain C write (f32/bf16). mode 1 (qkv): fused epilogue — per-wave
// 128x64 acc block = one 64-wide head slice; RMS+RoPE in-register (partner
// d+-32 = acc[m][nf^2][r], same lane), DIRECT global stores (no LDS).
__global__ __launch_bounds__(512, 2) void k_gemm256(
    const short* __restrict__ A, const short* __restrict__ Bt,
    void* __restrict__ Cout, int M, int N, int K, int outBf16,
    const float* __restrict__ trig,
    const float* __restrict__ qw, const float* __restrict__ kw,
    short* __restrict__ qb2, short* __restrict__ kb2, short* __restrict__ vtg,
    int mode) {
  __shared__ short sm[65536];                       // 128 KiB
  int nbn = N >> 8;
  int nwg = (M >> 8) * nbn;
  int bid = blockIdx.x;
  int swz = (bid & 7) * (nwg >> 3) + (bid >> 3);    // XCD swizzle (nwg % 8 == 0)
  int bm = swz / nbn, bn = swz % nbn;
  int tid = threadIdx.x, wid = tid >> 6, lane = tid & 63;
  int wm = wid >> 2, wn = wid & 3;
  int lo = lane & 15, hi = lane >> 4;
  int NT = K >> 6;                                  // # K-tiles (BK=64)

  // staging: thread covers (row r0, chunk dc) and (r0+64, dc) of a 128x8-chunk half
  int r0 = tid >> 3, dc = tid & 7;
  int sc = dc ^ (r0 & 7);                           // pre-swizzled source chunk
  const short* aS0 = A  + (size_t)(bm * 256 + r0) * K + sc * 8;        // half 0
  const short* bS0 = Bt + (size_t)(bn * 256 + r0) * K + sc * 8;
  size_t hstep = (size_t)128 * K;                   // half 1 = +128 rows

  auto stage = [&](int jt, int mat, int h, int d) {
    const short* s = (mat ? bS0 : aS0) + (size_t)h * hstep + jt * 64;
    short* l = sm + d * 32768 + mat * 16384 + h * 8192;
    gload16(s,                     l + tid * 8);
    gload16(s + (size_t)64 * K,    l + 4096 + tid * 8);
  };

  int aRd[2];
#pragma unroll
  for (int kk = 0; kk < 2; ++kk)
    aRd[kk] = lo * 64 + (((kk << 2) | hi) ^ (lo & 7)) * 8;

  short8 Afr[8][2];
  short8 Bfr[2][2];
  f32x4 acc[8][4] = {};

  auto rdA = [&](int d, int m0) {
    int base = d * 32768 + wm * 8192;
#pragma unroll
    for (int m = 0; m < 4; ++m)
#pragma unroll
      for (int kk = 0; kk < 2; ++kk)
        Afr[m0 + m][kk] = *(const short8*)&sm[base + (m0 + m) * 1024 + aRd[kk]];
  };
  auto rdB = [&](int d, int n0) {
    int base = d * 32768 + 16384 + (wn >> 1) * 8192 + (wn & 1) * 4096;
#pragma unroll
    for (int nf = 0; nf < 2; ++nf)
#pragma unroll
      for (int kk = 0; kk < 2; ++kk)
        Bfr[nf][kk] = *(const short8*)&sm[base + (n0 + nf) * 1024 + aRd[kk]];
  };
  auto quad = [&](int m0, int n0) {
    __builtin_amdgcn_s_setprio(1);
#pragma unroll
    for (int m = 0; m < 4; ++m)
#pragma unroll
      for (int j = 0; j < 2; ++j)
#pragma unroll
        for (int kk = 0; kk < 2; ++kk)
          acc[m0 + m][n0 + j] = mfma16(Afr[m0 + m][kk], Bfr[j][kk], acc[m0 + m][n0 + j]);
    __builtin_amdgcn_s_setprio(0);
  };

  stage(0, 0, 0, 0); stage(0, 1, 0, 0); stage(0, 0, 1, 0); stage(0, 1, 1, 0);
  if (NT > 1) { stage(1, 0, 0, 1); stage(1, 1, 0, 1); }
  VMCNT4;
  BARRIER;

#pragma unroll 2
  for (int jt = 0; jt < NT; ++jt) {
    int d = jt & 1;
    rdA(d, 0); rdB(d, 0);
    if (jt + 1 < NT) stage(jt + 1, 0, 1, d ^ 1);
    BARRIER; LGKM0;
    quad(0, 0);
    BARRIER;
    rdA(d, 4);
    if (jt + 1 < NT) stage(jt + 1, 1, 1, d ^ 1);
    BARRIER; LGKM0;
    quad(4, 0);
    BARRIER;
    rdB(d, 2);
    if (jt + 2 < NT) stage(jt + 2, 0, 0, d);
    BARRIER; LGKM0;
    quad(0, 2);
    BARRIER;
    if (jt + 2 < NT) stage(jt + 2, 1, 0, d);
    VMCNT4;
    BARRIER;
    quad(4, 2);
    BARRIER;
  }

  if (mode == 1) {
    // ---- fused qkv epilogue: RMS+RoPE (Q,K) / pass (V), direct global stores
    int tg0 = (bm * 256 + wm * 128) & 4095;          // token base (within batch)
    int bb  = (bm * 256) >> 12;                      // batch index
    bool isQ = bn < 4, isK = (bn == 4 && wn == 0), isV = (bn == 4 && wn == 1);
    if (isQ || isK) {
      const float* nw = isQ ? qw : kw;
      float w0 = nw[lo], w1 = nw[16 + lo], w2 = nw[32 + lo], w3 = nw[48 + lo];
      short* dst = isQ ? qb2 + (size_t)((bb * 16 + bn * 4 + wn) * 4096) * 64
                       : kb2 + (size_t)(bb * 4096) * 64;
      const float2* tb = (const float2*)trig;
#pragma unroll
      for (int m = 0; m < 8; ++m)
#pragma unroll
        for (int r = 0; r < 4; ++r) {
          float x0 = acc[m][0][r], x1 = acc[m][1][r];
          float x2 = acc[m][2][r], x3 = acc[m][3][r];
          float ss = x0 * x0 + x1 * x1 + x2 * x2 + x3 * x3;
          ss += __shfl_xor(ss, 1); ss += __shfl_xor(ss, 2);
          ss += __shfl_xor(ss, 4); ss += __shfl_xor(ss, 8);
          float rn = rsqrtf(ss * 0.015625f + 1e-6f);
          x0 *= rn * w0; x1 *= rn * w1; x2 *= rn * w2; x3 *= rn * w3;
          int tp = tg0 + m * 16 + hi * 4 + r;        // token (within batch)
          float2 cs0 = tb[tp * 32 + lo];
          float2 cs1 = tb[tp * 32 + 16 + lo];
          float o0 = x0 * cs0.x - x2 * cs0.y;        // d = lo
          float o1 = x1 * cs1.x - x3 * cs1.y;        // d = 16+lo
          float o2 = x2 * cs0.x + x0 * cs0.y;        // d = 32+lo
          float o3 = x3 * cs1.x + x1 * cs1.y;        // d = 48+lo
          size_t tb_ = (size_t)tp * 64;
          dst[tb_ + lo]      = (short)f2bf(o0);
          dst[tb_ + 16 + lo] = (short)f2bf(o1);
          dst[tb_ + 32 + lo] = (short)f2bf(o2);
          dst[tb_ + 48 + lo] = (short)f2bf(o3);
        }
    } else if (isV) {
      // thread holds 4 CONSECUTIVE tokens (r=0..3) per (m,nf) -> short4 stores
#pragma unroll
      for (int m = 0; m < 8; ++m)
#pragma unroll
        for (int nf = 0; nf < 4; ++nf) {
          int dd = nf * 16 + lo;
          short4 o;
          o.x = (short)f2bf(acc[m][nf][0]);
          o.y = (short)f2bf(acc[m][nf][1]);
          o.z = (short)f2bf(acc[m][nf][2]);
          o.w = (short)f2bf(acc[m][nf][3]);
          *(short4*)&vtg[((size_t)(bb * 64 + dd)) * 4096 + tg0 + m * 16 + hi * 4] = o;
        }
    }
    return;
  }

  // ---- mode 0: plain C write. layout col = lane&15, row = (lane>>4)*4 + reg
  int row0 = bm * 256 + wm * 128 + hi * 4;
  int col0 = bn * 256 + wn * 64 + lo;
  if (outBf16) {
    short* C = (short*)Cout;
#pragma unroll
    for (int m = 0; m < 8; ++m)
#pragma unroll
      for (int nf = 0; nf < 4; ++nf)
#pragma unroll
        for (int r = 0; r < 4; ++r)
          C[(size_t)(row0 + m * 16 + r) * N + col0 + nf * 16] = (short)f2bf(acc[m][nf][r]);
  } else {
    float* C = (float*)Cout;
#pragma unroll
    for (int m = 0; m < 8; ++m)
#pragma unroll
      for (int nf = 0; nf < 4; ++nf)
#pragma unroll
        for (int r = 0; r < 4; ++r)
          C[(size_t)(row0 + m * 16 + r) * N + col0 + nf * 16] = acc[m][nf][r];
  }
}

// ---------------- kernel: blocked sliding-window attention (swapped QK^T) ----
// grid 2048 = (b, n, h fastest). 4 waves x 32 q-rows. Per-32-key-subtile
// online softmax keeps only one f32x16 S live -> no VGPR spill at 128-reg cap.
__global__ __launch_bounds__(256, 4) void k_attn(const short* __restrict__ qb,
                                                 const short* __restrict__ kb,
                                                 const short* __restrict__ vtg,
                                                 short* __restrict__ y) {
  __shared__ __align__(16) char smem[33792];
  short* ks  = (short*)smem;            // [128 key][64 d], chunk-XOR swizzled
  short* vts = (short*)(smem + 16384);  // [64 d][128 key], chunk-XOR swizzled
  int bid = blockIdx.x;
  int swz = (bid & 7) * 256 + (bid >> 3);          // XCD swizzle
  int h = swz & 15, n = (swz >> 4) & 31, b = swz >> 9;
  int tid = threadIdx.x, wid = tid >> 6, lane = tid & 63;
  int lo = lane & 31, hi = lane >> 5;

  const short* qrow = qb + (size_t)((b * 16 + h) * 4096 + n * 128 + wid * 32 + lo) * 64;
  short8 aq[4];
#pragma unroll
  for (int s = 0; s < 4; ++s) aq[s] = *(const short8*)(qrow + s * 16 + hi * 8);

  f32x16 O0 = {}, O1 = {};                         // O^T: rows d / d+32, col q
  float mrun = -1e30f, lrun = 0.f;
  int qr = wid * 32 + lo;
  const float SC = 0.125f * 1.4426950408889634f;   // scale * log2(e)

  for (int hf = (n == 0) ? 1 : 0; hf < 2; ++hf) {  // n==0: half0 fully masked
    int tg = (n - 1 + hf) * 128;                   // first key token (within b)
#pragma unroll
    for (int p = 0; p < 4; ++p) {
      int idx = p * 256 + tid;
      int r = idx >> 3, dc = idx & 7;
      gload16(kb + (size_t)(b * 4096 + tg + r) * 64 + ((dc ^ (r & 7)) << 3),
              ks + idx * 8);
    }
#pragma unroll
    for (int p = 0; p < 4; ++p) {
      int idx = p * 256 + tid;
      int dd = idx >> 4, s = idx & 15;
      gload16(vtg + (size_t)(b * 64 + dd) * 4096 + tg + ((s ^ (dd & 7)) << 3),
              vts + idx * 8);
    }
    __syncthreads();

#pragma unroll
    for (int mt = 0; mt < 4; ++mt) {
      f32x16 S = {};
      int r = mt * 32 + lo;
#pragma unroll
      for (int kst = 0; kst < 4; ++kst) {
        short8 kf = *(const short8*)&ks[r * 64 + ((((kst << 1) | hi) ^ (r & 7)) << 3)];
        S = mfma32(kf, aq[kst], S);
      }
#pragma unroll
      for (int rr = 0; rr < 16; ++rr) {
        int kg = hf * 128 + mt * 32 + (rr & 3) + ((rr >> 2) << 3) + (hi << 2);
        S[rr] = (kg >= qr && kg <= qr + 128) ? S[rr] * SC : -30000.f;
      }
      float pmax = S[0];
#pragma unroll
      for (int rr = 1; rr < 16; ++rr) pmax = fmaxf(pmax, S[rr]);
      pmax = fmaxf(pmax, __shfl_xor(pmax, 32));
      if (!__all(pmax - mrun <= 8.f)) {
        float mn = fmaxf(mrun, pmax);
        float al = exp2f(mrun - mn);
        lrun *= al; mrun = mn;
#pragma unroll
        for (int rr = 0; rr < 16; ++rr) { O0[rr] *= al; O1[rr] *= al; }
      }
      float ls = 0.f;
#pragma unroll
      for (int rr = 0; rr < 16; ++rr) { S[rr] = exp2f(S[rr] - mrun); ls += S[rr]; }
      ls += __shfl_xor(ls, 32);
      lrun += ls;
#pragma unroll
      for (int h2 = 0; h2 < 2; ++h2) {
        int b0 = h2 * 8;
        unsigned pk0 = cvtpk(S[b0 + 0], S[b0 + 1]);
        unsigned pk1 = cvtpk(S[b0 + 2], S[b0 + 3]);
        unsigned pk2 = cvtpk(S[b0 + 4], S[b0 + 5]);
        unsigned pk3 = cvtpk(S[b0 + 6], S[b0 + 7]);
        asm("v_permlane32_swap_b32 %0, %1" : "+v"(pk0), "+v"(pk2));
        asm("v_permlane32_swap_b32 %0, %1" : "+v"(pk1), "+v"(pk3));
        uint4v uw; uw.x = pk0; uw.y = pk1; uw.z = pk2; uw.w = pk3;
        short8 pb = __builtin_bit_cast(short8, uw);
        int kc = mt * 4 + h2 * 2 + hi;
        short8 vb0 = *(const short8*)&vts[lo * 128 + ((kc ^ (lo & 7)) << 3)];
        short8 vb1 = *(const short8*)&vts[(32 + lo) * 128 + ((kc ^ (lo & 7)) << 3)];
        O0 = mfma32(vb0, pb, O0);
        O1 = mfma32(vb1, pb, O1);
      }
    }
    __syncthreads();
  }

  float inv = 1.f / lrun;
  float* ot = (float*)smem + wid * 2112;           // [64 d][33] per wave
#pragma unroll
  for (int r = 0; r < 16; ++r) {
    int d0 = (r & 3) + ((r >> 2) << 3) + (hi << 2);
    ot[d0 * 33 + lo]        = O0[r] * inv;
    ot[(d0 + 32) * 33 + lo] = O1[r] * inv;
  }
  __syncthreads();
  int tok = lane >> 3, dc = lane & 7;
#pragma unroll
  for (int g = 0; g < 4; ++g) {
    int q = g * 8 + tok;
    short8 o8;
#pragma unroll
    for (int jj = 0; jj < 8; ++jj)
      o8[jj] = (short)f2bf(ot[(dc * 8 + jj) * 33 + q]);
    *(short8*)&y[(size_t)(b * 4096 + n * 128 + wid * 32 + q) * 1024 + h * 64 + dc * 8] = o8;
  }
}

// ---------------- launch ----------------
extern "C" void kernel_launch(void* const* d_in, const int* in_sizes, int n_in,
                              void* d_out, int out_size, void* d_ws, size_t ws_size,
                              hipStream_t stream) {
  const float* x      = (const float*)d_in[0];
  const int*   pos    = (const int*)d_in[1];
  const float* w_attn = (const float*)d_in[2];
  const float* w_proj = (const float*)d_in[3];
  const float* qw     = (const float*)d_in[4];
  const float* kw     = (const float*)d_in[5];

  char* ws = (char*)d_ws;
  short* xb   = (short*)ws;                         // 33,554,432 B (aliased as y later)
  short* wabt = (short*)(ws + 33554432);            //  2,621,440 B (1280 x 1024, pad rows untouched)
  short* wpbt = (short*)(ws + 36175872);            //  2,097,152 B
  short* qb2  = (short*)(ws + 38273024);            // 33,554,432 B
  short* kb2  = (short*)(ws + 71827456);            //  2,097,152 B
  short* vtg  = (short*)(ws + 73924608);            //  2,097,152 B
  float* trig = (float*)(ws + 76021760);            //  1,048,576 B (cos,sin interleaved)
  short* ybuf = xb;                                 // xb dead after qkv GEMM

  hipLaunchKernelGGL(k_cvt, dim3(16384), dim3(256), 0, stream, x, xb, 4194304);
  hipLaunchKernelGGL(k_tcvt, dim3(32, 36), dim3(256), 0, stream, w_attn, wabt, 1024, 1152);
  hipLaunchKernelGGL(k_tcvt, dim3(32, 32), dim3(256), 0, stream, w_proj, wpbt, 1024, 1024);
  hipLaunchKernelGGL(k_trig, dim3(512), dim3(256), 0, stream, pos, trig);
  hipLaunchKernelGGL(k_gemm256, dim3(320), dim3(512), 0, stream, xb, wabt,
                     (void*)nullptr, 16384, 1280, 1024, 1,
                     trig, qw, kw, qb2, kb2, vtg, 1);
  hipLaunchKernelGGL(k_attn, dim3(2048), dim3(256), 0, stream, qb2, kb2, vtg, ybuf);
  hipLaunchKernelGGL(k_gemm256, dim3(256), dim3(512), 0, stream, ybuf, wpbt, d_out,
                     16384, 1024, 1024, 0,
                     (const float*)nullptr, (const float*)nullptr,
                     (const float*)nullptr,
                     (short*)nullptr, (short*)nullptr, (short*)nullptr, 0);
}

// Round 9
// 167.699 us; speedup vs baseline: 1.1809x; 1.0467x over previous
//
#include <hip/hip_runtime.h>

// MQA fused layer, MI355X gfx950.
// B=4 T=4096 C=1024 H=16 D=64 W=128 NB=32.
// Pipeline: cvt(x)->bf16 | transpose-cvt weights | trig table |
//           KV-GEMM 128^2 (fused RMS+RoPE K / V-transpose epilogue) |
//           Q-GEMM 256^2 (fused RMS+RoPE epilogue, 256 blocks = 1 round) |
//           blocked sliding-window attention | GEMM proj 256^2.

typedef __attribute__((ext_vector_type(8))) short short8;
typedef __attribute__((ext_vector_type(4))) float f32x4;
typedef __attribute__((ext_vector_type(16))) float f32x16;
typedef __attribute__((ext_vector_type(4))) unsigned uint4v;

#define DEV static __device__ __forceinline__

DEV unsigned short f2bf(float f) {           // fp32 -> bf16 RNE
  unsigned u = __builtin_bit_cast(unsigned, f);
  u += 0x7fffu + ((u >> 16) & 1u);
  return (unsigned short)(u >> 16);
}
DEV float bf2f(unsigned short s) {
  unsigned u = ((unsigned)s) << 16;
  return __builtin_bit_cast(float, u);
}
DEV unsigned cvtpk(float a, float b) {       // {bf16(a), bf16(b)} packed
  unsigned r;
  asm("v_cvt_pk_bf16_f32 %0, %1, %2" : "=v"(r) : "v"(a), "v"(b));
  return r;
}

DEV f32x4 mfma16(short8 a, short8 b, f32x4 c) {
  return __builtin_amdgcn_mfma_f32_16x16x32_bf16(a, b, c, 0, 0, 0);
}
DEV f32x16 mfma32(short8 a, short8 b, f32x16 c) {
  return __builtin_amdgcn_mfma_f32_32x32x16_bf16(a, b, c, 0, 0, 0);
}

// async global->LDS, 16B per lane
DEV void gload16(const void* g, void* l) {
  __builtin_amdgcn_global_load_lds(
      (const __attribute__((address_space(1))) unsigned int*)(unsigned long long)g,
      (__attribute__((address_space(3))) unsigned int*)(unsigned int)(unsigned long long)l,
      16, 0, 0);
}

#define BARRIER __builtin_amdgcn_s_barrier()
#define LGKM0  asm volatile("s_waitcnt lgkmcnt(0)" ::: "memory")
#define VMCNT4 asm volatile("s_waitcnt vmcnt(4)" ::: "memory")

// ---------------- kernel: f32 -> bf16 elementwise ----------------
__global__ __launch_bounds__(256) void k_cvt(const float* __restrict__ in,
                                             short* __restrict__ out, int n4) {
  int i = blockIdx.x * 256 + threadIdx.x;
  if (i >= n4) return;
  float4 v = ((const float4*)in)[i];
  short4 o;
  o.x = (short)f2bf(v.x); o.y = (short)f2bf(v.y);
  o.z = (short)f2bf(v.z); o.w = (short)f2bf(v.w);
  ((short4*)out)[i] = o;
}

// ---------------- kernel: W (KxN f32) -> Wt (NxK bf16) ----------------
__global__ __launch_bounds__(256) void k_tcvt(const float* __restrict__ W,
                                              short* __restrict__ Wt, int K, int N) {
  __shared__ float tl[32][33];
  int tx = threadIdx.x & 31, ty = threadIdx.x >> 5;   // 32 x 8
  int k0 = blockIdx.x * 32, n0 = blockIdx.y * 32;
#pragma unroll
  for (int i = 0; i < 4; ++i)
    tl[ty + i * 8][tx] = W[(size_t)(k0 + ty + i * 8) * N + n0 + tx];
  __syncthreads();
#pragma unroll
  for (int i = 0; i < 4; ++i)
    Wt[(size_t)(n0 + ty + i * 8) * K + k0 + tx] = (short)f2bf(tl[tx][ty + i * 8]);
}

// ---------------- kernel: RoPE (cos,sin) interleaved table [4096][32] --------
__global__ __launch_bounds__(256) void k_trig(const int* __restrict__ pos,
                                              float* __restrict__ tbl) {
  int idx = blockIdx.x * 256 + threadIdx.x;          // 131072 = 4096*32
  int t = idx >> 5, j = idx & 31;
  float invf = __expf((float)j * (-13.815510558f / 32.f));
  float p = (float)pos[t * 3 + (j % 3)];
  float s, c;
  sincosf(p * invf, &s, &c);
  ((float2*)tbl)[idx] = make_float2(c, s);
}

// ---------------- kernel: KV GEMM 128x128 (m97 structure) + fused epilogue --
// A: 16384xK bf16 (x). Bt: 128xK bf16 (w_attn cols 1024..1151 transposed).
// cols 0..63 = K head -> RMS+RoPE -> kb2[b][t][d]; 64..127 = V -> vtg[b][d][t].
__global__ __launch_bounds__(256) void k_gemmkv(const short* __restrict__ A,
                                                const short* __restrict__ Bt,
                                                const float* __restrict__ trig,
                                                const float* __restrict__ kw,
                                                short* __restrict__ kb2,
                                                short* __restrict__ vtg) {
  __shared__ short As[128 * 32];
  __shared__ short Bs[128 * 32];
  const int K = 1024;
  int bid = blockIdx.x;
  int bm = (bid & 7) * 16 + (bid >> 3);            // XCD swizzle, nwg=128
  int tid = threadIdx.x, lane = tid & 63, wid = tid >> 6;
  int wr = wid >> 1, wc = wid & 1;
  int lo = lane & 15, hi = lane >> 4;
  const short* Ab = A + (size_t)(bm * 128 + (tid >> 2)) * K + (tid & 3) * 8;
  const short* Bb = Bt + (size_t)(tid >> 2) * K + (tid & 3) * 8;
  f32x4 acc[4][4] = {};
  for (int kt = 0; kt < K; kt += 32) {
    gload16(Ab + kt,            As + tid * 8);
    gload16(Ab + kt + 64 * K,   As + 2048 + tid * 8);
    gload16(Bb + kt,            Bs + tid * 8);
    gload16(Bb + kt + 64 * K,   Bs + 2048 + tid * 8);
    __syncthreads();
    short8 a[4], b[4];
#pragma unroll
    for (int m = 0; m < 4; ++m)
      a[m] = *(const short8*)&As[(wr * 64 + m * 16 + lo) * 32 + hi * 8];
#pragma unroll
    for (int n = 0; n < 4; ++n)
      b[n] = *(const short8*)&Bs[(wc * 64 + n * 16 + lo) * 32 + hi * 8];
#pragma unroll
    for (int m = 0; m < 4; ++m)
#pragma unroll
      for (int n = 0; n < 4; ++n)
        acc[m][n] = mfma16(a[m], b[n], acc[m][n]);
    __syncthreads();
  }
  // epilogue: token tp = bm*128 + wr*64 + m*16 + hi*4 + r ; d = n*16 + lo
  int tg0 = (bm * 128 + wr * 64) & 4095;
  int bb  = (bm * 128) >> 12;
  if (wc == 0) {                                   // K head: RMS + RoPE
    float w0 = kw[lo], w1 = kw[16 + lo], w2 = kw[32 + lo], w3 = kw[48 + lo];
    const float2* tb = (const float2*)trig;
#pragma unroll
    for (int m = 0; m < 4; ++m)
#pragma unroll
      for (int r = 0; r < 4; ++r) {
        float x0 = acc[m][0][r], x1 = acc[m][1][r];
        float x2 = acc[m][2][r], x3 = acc[m][3][r];
        float ss = x0 * x0 + x1 * x1 + x2 * x2 + x3 * x3;
        ss += __shfl_xor(ss, 1); ss += __shfl_xor(ss, 2);
        ss += __shfl_xor(ss, 4); ss += __shfl_xor(ss, 8);
        float rn = rsqrtf(ss * 0.015625f + 1e-6f);
        x0 *= rn * w0; x1 *= rn * w1; x2 *= rn * w2; x3 *= rn * w3;
        int tp = tg0 + m * 16 + hi * 4 + r;
        float2 cs0 = tb[tp * 32 + lo];
        float2 cs1 = tb[tp * 32 + 16 + lo];
        float o0 = x0 * cs0.x - x2 * cs0.y;
        float o1 = x1 * cs1.x - x3 * cs1.y;
        float o2 = x2 * cs0.x + x0 * cs0.y;
        float o3 = x3 * cs1.x + x1 * cs1.y;
        size_t tb_ = ((size_t)bb * 4096 + tp) * 64;
        kb2[tb_ + lo]      = (short)f2bf(o0);
        kb2[tb_ + 16 + lo] = (short)f2bf(o1);
        kb2[tb_ + 32 + lo] = (short)f2bf(o2);
        kb2[tb_ + 48 + lo] = (short)f2bf(o3);
      }
  } else {                                         // V: transpose to [d][t]
#pragma unroll
    for (int m = 0; m < 4; ++m)
#pragma unroll
      for (int nf = 0; nf < 4; ++nf) {
        int dd = nf * 16 + lo;
        short4 o;
        o.x = (short)f2bf(acc[m][nf][0]);
        o.y = (short)f2bf(acc[m][nf][1]);
        o.z = (short)f2bf(acc[m][nf][2]);
        o.w = (short)f2bf(acc[m][nf][3]);
        *(short4*)&vtg[((size_t)(bb * 64 + dd)) * 4096 + tg0 + m * 16 + hi * 4] = o;
      }
  }
}

// ---------------- kernel: 256x256x64 bf16 GEMM, 8-phase schedule ------------
// mode 0: plain C write (f32/bf16). mode 1 (Q): fused RMS+RoPE epilogue,
// every wave = one head slice of 128 tokens, direct global stores -> qb2.
__global__ __launch_bounds__(512, 2) void k_gemm256(
    const short* __restrict__ A, const short* __restrict__ Bt,
    void* __restrict__ Cout, int M, int N, int K, int outBf16,
    const float* __restrict__ trig, const float* __restrict__ qw,
    short* __restrict__ qb2, int mode) {
  __shared__ short sm[65536];                       // 128 KiB
  int nbn = N >> 8;
  int nwg = (M >> 8) * nbn;
  int bid = blockIdx.x;
  int swz = (bid & 7) * (nwg >> 3) + (bid >> 3);    // XCD swizzle (nwg % 8 == 0)
  int bm = swz / nbn, bn = swz % nbn;
  int tid = threadIdx.x, wid = tid >> 6, lane = tid & 63;
  int wm = wid >> 2, wn = wid & 3;
  int lo = lane & 15, hi = lane >> 4;
  int NT = K >> 6;                                  // # K-tiles (BK=64)

  int r0 = tid >> 3, dc = tid & 7;
  int sc = dc ^ (r0 & 7);                           // pre-swizzled source chunk
  const short* aS0 = A  + (size_t)(bm * 256 + r0) * K + sc * 8;
  const short* bS0 = Bt + (size_t)(bn * 256 + r0) * K + sc * 8;
  size_t hstep = (size_t)128 * K;

  auto stage = [&](int jt, int mat, int h, int d) {
    const short* s = (mat ? bS0 : aS0) + (size_t)h * hstep + jt * 64;
    short* l = sm + d * 32768 + mat * 16384 + h * 8192;
    gload16(s,                     l + tid * 8);
    gload16(s + (size_t)64 * K,    l + 4096 + tid * 8);
  };

  int aRd[2];
#pragma unroll
  for (int kk = 0; kk < 2; ++kk)
    aRd[kk] = lo * 64 + (((kk << 2) | hi) ^ (lo & 7)) * 8;

  short8 Afr[8][2];
  short8 Bfr[2][2];
  f32x4 acc[8][4] = {};

  auto rdA = [&](int d, int m0) {
    int base = d * 32768 + wm * 8192;
#pragma unroll
    for (int m = 0; m < 4; ++m)
#pragma unroll
      for (int kk = 0; kk < 2; ++kk)
        Afr[m0 + m][kk] = *(const short8*)&sm[base + (m0 + m) * 1024 + aRd[kk]];
  };
  auto rdB = [&](int d, int n0) {
    int base = d * 32768 + 16384 + (wn >> 1) * 8192 + (wn & 1) * 4096;
#pragma unroll
    for (int nf = 0; nf < 2; ++nf)
#pragma unroll
      for (int kk = 0; kk < 2; ++kk)
        Bfr[nf][kk] = *(const short8*)&sm[base + (n0 + nf) * 1024 + aRd[kk]];
  };
  auto quad = [&](int m0, int n0) {
    __builtin_amdgcn_s_setprio(1);
#pragma unroll
    for (int m = 0; m < 4; ++m)
#pragma unroll
      for (int j = 0; j < 2; ++j)
#pragma unroll
        for (int kk = 0; kk < 2; ++kk)
          acc[m0 + m][n0 + j] = mfma16(Afr[m0 + m][kk], Bfr[j][kk], acc[m0 + m][n0 + j]);
    __builtin_amdgcn_s_setprio(0);
  };

  stage(0, 0, 0, 0); stage(0, 1, 0, 0); stage(0, 0, 1, 0); stage(0, 1, 1, 0);
  if (NT > 1) { stage(1, 0, 0, 1); stage(1, 1, 0, 1); }
  VMCNT4;
  BARRIER;

#pragma unroll 2
  for (int jt = 0; jt < NT; ++jt) {
    int d = jt & 1;
    rdA(d, 0); rdB(d, 0);
    if (jt + 1 < NT) stage(jt + 1, 0, 1, d ^ 1);
    BARRIER; LGKM0;
    quad(0, 0);
    BARRIER;
    rdA(d, 4);
    if (jt + 1 < NT) stage(jt + 1, 1, 1, d ^ 1);
    BARRIER; LGKM0;
    quad(4, 0);
    BARRIER;
    rdB(d, 2);
    if (jt + 2 < NT) stage(jt + 2, 0, 0, d);
    BARRIER; LGKM0;
    quad(0, 2);
    BARRIER;
    if (jt + 2 < NT) stage(jt + 2, 1, 0, d);
    VMCNT4;
    BARRIER;
    quad(4, 2);
    BARRIER;
  }

  if (mode == 1) {
    // ---- fused Q epilogue: RMS+RoPE, direct global stores (no LDS)
    int tg0 = (bm * 256 + wm * 128) & 4095;          // token base (within batch)
    int bb  = (bm * 256) >> 12;                      // batch index
    int hh  = bn * 4 + wn;                           // head 0..15
    float w0 = qw[lo], w1 = qw[16 + lo], w2 = qw[32 + lo], w3 = qw[48 + lo];
    short* dst = qb2 + (size_t)((bb * 16 + hh) * 4096) * 64;
    const float2* tb = (const float2*)trig;
#pragma unroll
    for (int m = 0; m < 8; ++m)
#pragma unroll
      for (int r = 0; r < 4; ++r) {
        float x0 = acc[m][0][r], x1 = acc[m][1][r];
        float x2 = acc[m][2][r], x3 = acc[m][3][r];
        float ss = x0 * x0 + x1 * x1 + x2 * x2 + x3 * x3;
        ss += __shfl_xor(ss, 1); ss += __shfl_xor(ss, 2);
        ss += __shfl_xor(ss, 4); ss += __shfl_xor(ss, 8);
        float rn = rsqrtf(ss * 0.015625f + 1e-6f);
        x0 *= rn * w0; x1 *= rn * w1; x2 *= rn * w2; x3 *= rn * w3;
        int tp = tg0 + m * 16 + hi * 4 + r;
        float2 cs0 = tb[tp * 32 + lo];
        float2 cs1 = tb[tp * 32 + 16 + lo];
        float o0 = x0 * cs0.x - x2 * cs0.y;
        float o1 = x1 * cs1.x - x3 * cs1.y;
        float o2 = x2 * cs0.x + x0 * cs0.y;
        float o3 = x3 * cs1.x + x1 * cs1.y;
        size_t tb_ = (size_t)tp * 64;
        dst[tb_ + lo]      = (short)f2bf(o0);
        dst[tb_ + 16 + lo] = (short)f2bf(o1);
        dst[tb_ + 32 + lo] = (short)f2bf(o2);
        dst[tb_ + 48 + lo] = (short)f2bf(o3);
      }
    return;
  }

  // ---- mode 0: plain C write. layout col = lane&15, row = (lane>>4)*4 + reg
  int row0 = bm * 256 + wm * 128 + hi * 4;
  int col0 = bn * 256 + wn * 64 + lo;
  if (outBf16) {
    short* C = (short*)Cout;
#pragma unroll
    for (int m = 0; m < 8; ++m)
#pragma unroll
      for (int nf = 0; nf < 4; ++nf)
#pragma unroll
        for (int r = 0; r < 4; ++r)
          C[(size_t)(row0 + m * 16 + r) * N + col0 + nf * 16] = (short)f2bf(acc[m][nf][r]);
  } else {
    float* C = (float*)Cout;
#pragma unroll
    for (int m = 0; m < 8; ++m)
#pragma unroll
      for (int nf = 0; nf < 4; ++nf)
#pragma unroll
        for (int r = 0; r < 4; ++r)
          C[(size_t)(row0 + m * 16 + r) * N + col0 + nf * 16] = acc[m][nf][r];
  }
}

// ---------------- kernel: blocked sliding-window attention (swapped QK^T) ----
// grid 2048 = (b, n, h fastest). 4 waves x 32 q-rows. Per-32-key-subtile
// online softmax keeps only one f32x16 S live -> no VGPR spill at 128-reg cap.
__global__ __launch_bounds__(256, 4) void k_attn(const short* __restrict__ qb,
                                                 const short* __restrict__ kb,
                                                 const short* __restrict__ vtg,
                                                 short* __restrict__ y) {
  __shared__ __align__(16) char smem[33792];
  short* ks  = (short*)smem;            // [128 key][64 d], chunk-XOR swizzled
  short* vts = (short*)(smem + 16384);  // [64 d][128 key], chunk-XOR swizzled
  int bid = blockIdx.x;
  int swz = (bid & 7) * 256 + (bid >> 3);          // XCD swizzle
  int h = swz & 15, n = (swz >> 4) & 31, b = swz >> 9;
  int tid = threadIdx.x, wid = tid >> 6, lane = tid & 63;
  int lo = lane & 31, hi = lane >> 5;

  const short* qrow = qb + (size_t)((b * 16 + h) * 4096 + n * 128 + wid * 32 + lo) * 64;
  short8 aq[4];
#pragma unroll
  for (int s = 0; s < 4; ++s) aq[s] = *(const short8*)(qrow + s * 16 + hi * 8);

  f32x16 O0 = {}, O1 = {};                         // O^T: rows d / d+32, col q
  float mrun = -1e30f, lrun = 0.f;
  int qr = wid * 32 + lo;
  const float SC = 0.125f * 1.4426950408889634f;   // scale * log2(e)

  for (int hf = (n == 0) ? 1 : 0; hf < 2; ++hf) {  // n==0: half0 fully masked
    int tg = (n - 1 + hf) * 128;                   // first key token (within b)
#pragma unroll
    for (int p = 0; p < 4; ++p) {
      int idx = p * 256 + tid;
      int r = idx >> 3, dc = idx & 7;
      gload16(kb + (size_t)(b * 4096 + tg + r) * 64 + ((dc ^ (r & 7)) << 3),
              ks + idx * 8);
    }
#pragma unroll
    for (int p = 0; p < 4; ++p) {
      int idx = p * 256 + tid;
      int dd = idx >> 4, s = idx & 15;
      gload16(vtg + (size_t)(b * 64 + dd) * 4096 + tg + ((s ^ (dd & 7)) << 3),
              vts + idx * 8);
    }
    __syncthreads();

#pragma unroll
    for (int mt = 0; mt < 4; ++mt) {
      f32x16 S = {};
      int r = mt * 32 + lo;
#pragma unroll
      for (int kst = 0; kst < 4; ++kst) {
        short8 kf = *(const short8*)&ks[r * 64 + ((((kst << 1) | hi) ^ (r & 7)) << 3)];
        S = mfma32(kf, aq[kst], S);
      }
#pragma unroll
      for (int rr = 0; rr < 16; ++rr) {
        int kg = hf * 128 + mt * 32 + (rr & 3) + ((rr >> 2) << 3) + (hi << 2);
        S[rr] = (kg >= qr && kg <= qr + 128) ? S[rr] * SC : -30000.f;
      }
      float pmax = S[0];
#pragma unroll
      for (int rr = 1; rr < 16; ++rr) pmax = fmaxf(pmax, S[rr]);
      pmax = fmaxf(pmax, __shfl_xor(pmax, 32));
      if (!__all(pmax - mrun <= 8.f)) {
        float mn = fmaxf(mrun, pmax);
        float al = exp2f(mrun - mn);
        lrun *= al; mrun = mn;
#pragma unroll
        for (int rr = 0; rr < 16; ++rr) { O0[rr] *= al; O1[rr] *= al; }
      }
      float ls = 0.f;
#pragma unroll
      for (int rr = 0; rr < 16; ++rr) { S[rr] = exp2f(S[rr] - mrun); ls += S[rr]; }
      ls += __shfl_xor(ls, 32);
      lrun += ls;
#pragma unroll
      for (int h2 = 0; h2 < 2; ++h2) {
        int b0 = h2 * 8;
        unsigned pk0 = cvtpk(S[b0 + 0], S[b0 + 1]);
        unsigned pk1 = cvtpk(S[b0 + 2], S[b0 + 3]);
        unsigned pk2 = cvtpk(S[b0 + 4], S[b0 + 5]);
        unsigned pk3 = cvtpk(S[b0 + 6], S[b0 + 7]);
        asm("v_permlane32_swap_b32 %0, %1" : "+v"(pk0), "+v"(pk2));
        asm("v_permlane32_swap_b32 %0, %1" : "+v"(pk1), "+v"(pk3));
        uint4v uw; uw.x = pk0; uw.y = pk1; uw.z = pk2; uw.w = pk3;
        short8 pb = __builtin_bit_cast(short8, uw);
        int kc = mt * 4 + h2 * 2 + hi;
        short8 vb0 = *(const short8*)&vts[lo * 128 + ((kc ^ (lo & 7)) << 3)];
        short8 vb1 = *(const short8*)&vts[(32 + lo) * 128 + ((kc ^ (lo & 7)) << 3)];
        O0 = mfma32(vb0, pb, O0);
        O1 = mfma32(vb1, pb, O1);
      }
    }
    __syncthreads();
  }

  float inv = 1.f / lrun;
  float* ot = (float*)smem + wid * 2112;           // [64 d][33] per wave
#pragma unroll
  for (int r = 0; r < 16; ++r) {
    int d0 = (r & 3) + ((r >> 2) << 3) + (hi << 2);
    ot[d0 * 33 + lo]        = O0[r] * inv;
    ot[(d0 + 32) * 33 + lo] = O1[r] * inv;
  }
  __syncthreads();
  int tok = lane >> 3, dc = lane & 7;
#pragma unroll
  for (int g = 0; g < 4; ++g) {
    int q = g * 8 + tok;
    short8 o8;
#pragma unroll
    for (int jj = 0; jj < 8; ++jj)
      o8[jj] = (short)f2bf(ot[(dc * 8 + jj) * 33 + q]);
    *(short8*)&y[(size_t)(b * 4096 + n * 128 + wid * 32 + q) * 1024 + h * 64 + dc * 8] = o8;
  }
}

// ---------------- launch ----------------
extern "C" void kernel_launch(void* const* d_in, const int* in_sizes, int n_in,
                              void* d_out, int out_size, void* d_ws, size_t ws_size,
                              hipStream_t stream) {
  const float* x      = (const float*)d_in[0];
  const int*   pos    = (const int*)d_in[1];
  const float* w_attn = (const float*)d_in[2];
  const float* w_proj = (const float*)d_in[3];
  const float* qw     = (const float*)d_in[4];
  const float* kw     = (const float*)d_in[5];

  char* ws = (char*)d_ws;
  short* xb   = (short*)ws;                         // 33,554,432 B (aliased as y later)
  short* wabt = (short*)(ws + 33554432);            //  2,359,296 B (1152 x 1024)
  short* wpbt = (short*)(ws + 35913728);            //  2,097,152 B
  short* qb2  = (short*)(ws + 38010880);            // 33,554,432 B
  short* kb2  = (short*)(ws + 71565312);            //  2,097,152 B
  short* vtg  = (short*)(ws + 73662464);            //  2,097,152 B
  float* trig = (float*)(ws + 75759616);            //  1,048,576 B (cos,sin pairs)
  short* ybuf = xb;                                 // xb dead after Q/KV GEMMs

  hipLaunchKernelGGL(k_cvt, dim3(16384), dim3(256), 0, stream, x, xb, 4194304);
  hipLaunchKernelGGL(k_tcvt, dim3(32, 36), dim3(256), 0, stream, w_attn, wabt, 1024, 1152);
  hipLaunchKernelGGL(k_tcvt, dim3(32, 32), dim3(256), 0, stream, w_proj, wpbt, 1024, 1024);
  hipLaunchKernelGGL(k_trig, dim3(512), dim3(256), 0, stream, pos, trig);
  hipLaunchKernelGGL(k_gemmkv, dim3(128), dim3(256), 0, stream, xb,
                     wabt + (size_t)1024 * 1024, trig, kw, kb2, vtg);
  hipLaunchKernelGGL(k_gemm256, dim3(256), dim3(512), 0, stream, xb, wabt,
                     (void*)nullptr, 16384, 1024, 1024, 1, trig, qw, qb2, 1);
  hipLaunchKernelGGL(k_attn, dim3(2048), dim3(256), 0, stream, qb2, kb2, vtg, ybuf);
  hipLaunchKernelGGL(k_gemm256, dim3(256), dim3(512), 0, stream, ybuf, wpbt, d_out,
                     16384, 1024, 1024, 0,
                     (const float*)nullptr, (const float*)nullptr,
                     (short*)nullptr, 0);
}

// Round 10
// 160.155 us; speedup vs baseline: 1.2365x; 1.0471x over previous
//
#include <hip/hip_runtime.h>

// MQA fused layer, MI355X gfx950.
// B=4 T=4096 C=1024 H=16 D=64 W=128 NB=32.
// Pipeline: prep (cvt x, transpose-cvt weights, trig table — one dispatch) |
//           KV-GEMM 128^2 (fused RMS+RoPE K / V-transpose epilogue) |
//           Q-GEMM 256^2 depth-1-pipelined (fused RMS+RoPE epilogue) |
//           blocked sliding-window attention | proj GEMM 256^2 -> d_out.

typedef __attribute__((ext_vector_type(8))) short short8;
typedef __attribute__((ext_vector_type(4))) float f32x4;
typedef __attribute__((ext_vector_type(16))) float f32x16;
typedef __attribute__((ext_vector_type(4))) unsigned uint4v;

#define DEV static __device__ __forceinline__

DEV unsigned short f2bf(float f) {           // fp32 -> bf16 RNE
  unsigned u = __builtin_bit_cast(unsigned, f);
  u += 0x7fffu + ((u >> 16) & 1u);
  return (unsigned short)(u >> 16);
}
DEV float bf2f(unsigned short s) {
  unsigned u = ((unsigned)s) << 16;
  return __builtin_bit_cast(float, u);
}
DEV unsigned cvtpk(float a, float b) {       // {bf16(a), bf16(b)} packed
  unsigned r;
  asm("v_cvt_pk_bf16_f32 %0, %1, %2" : "=v"(r) : "v"(a), "v"(b));
  return r;
}

DEV f32x4 mfma16(short8 a, short8 b, f32x4 c) {
  return __builtin_amdgcn_mfma_f32_16x16x32_bf16(a, b, c, 0, 0, 0);
}
DEV f32x16 mfma32(short8 a, short8 b, f32x16 c) {
  return __builtin_amdgcn_mfma_f32_32x32x16_bf16(a, b, c, 0, 0, 0);
}

// async global->LDS, 16B per lane
DEV void gload16(const void* g, void* l) {
  __builtin_amdgcn_global_load_lds(
      (const __attribute__((address_space(1))) unsigned int*)(unsigned long long)g,
      (__attribute__((address_space(3))) unsigned int*)(unsigned int)(unsigned long long)l,
      16, 0, 0);
}

// ---------------- kernel: merged prep (cvt x | tcvt w_attn | tcvt w_proj |
//                  trig table) — one dispatch, branch by block range ----------
__global__ __launch_bounds__(256) void k_prep(const float* __restrict__ x,
                                              short* __restrict__ xb,
                                              const float* __restrict__ wa,
                                              short* __restrict__ wabt,
                                              const float* __restrict__ wp,
                                              short* __restrict__ wpbt,
                                              const int* __restrict__ pos,
                                              float* __restrict__ trig) {
  __shared__ float tl[32][33];
  int bid = blockIdx.x, tid = threadIdx.x;
  if (bid < 16384) {                                 // cvt x -> bf16
    int i = bid * 256 + tid;
    float4 v = ((const float4*)x)[i];
    short4 o;
    o.x = (short)f2bf(v.x); o.y = (short)f2bf(v.y);
    o.z = (short)f2bf(v.z); o.w = (short)f2bf(v.w);
    ((short4*)xb)[i] = o;
    return;
  }
  if (bid < 16384 + 1152 + 1024) {                   // transpose-cvt weights
    const float* W; short* Wt; int N, local;
    if (bid < 16384 + 1152) { local = bid - 16384; W = wa; Wt = wabt; N = 1152; }
    else { local = bid - 16384 - 1152; W = wp; Wt = wpbt; N = 1024; }
    int k0 = (local & 31) * 32, n0 = (local >> 5) * 32;
    int tx = tid & 31, ty = tid >> 5;
#pragma unroll
    for (int i = 0; i < 4; ++i)
      tl[ty + i * 8][tx] = W[(size_t)(k0 + ty + i * 8) * N + n0 + tx];
    __syncthreads();
#pragma unroll
    for (int i = 0; i < 4; ++i)
      Wt[(size_t)(n0 + ty + i * 8) * 1024 + k0 + tx] = (short)f2bf(tl[tx][ty + i * 8]);
    return;
  }
  {                                                  // trig table [4096][32]
    int idx = (bid - 16384 - 1152 - 1024) * 256 + tid;
    int t = idx >> 5, j = idx & 31;
    float invf = __expf((float)j * (-13.815510558f / 32.f));
    float p = (float)pos[t * 3 + (j % 3)];
    float s, c;
    sincosf(p * invf, &s, &c);
    ((float2*)trig)[idx] = make_float2(c, s);
  }
}

// ---------------- kernel: KV GEMM 128x128 (m97 structure) + fused epilogue --
__global__ __launch_bounds__(256) void k_gemmkv(const short* __restrict__ A,
                                                const short* __restrict__ Bt,
                                                const float* __restrict__ trig,
                                                const float* __restrict__ kw,
                                                short* __restrict__ kb2,
                                                short* __restrict__ vtg) {
  __shared__ short As[128 * 32];
  __shared__ short Bs[128 * 32];
  const int K = 1024;
  int bid = blockIdx.x;
  int bm = (bid & 7) * 16 + (bid >> 3);            // XCD swizzle, nwg=128
  int tid = threadIdx.x, lane = tid & 63, wid = tid >> 6;
  int wr = wid >> 1, wc = wid & 1;
  int lo = lane & 15, hi = lane >> 4;
  const short* Ab = A + (size_t)(bm * 128 + (tid >> 2)) * K + (tid & 3) * 8;
  const short* Bb = Bt + (size_t)(tid >> 2) * K + (tid & 3) * 8;
  f32x4 acc[4][4] = {};
  for (int kt = 0; kt < K; kt += 32) {
    gload16(Ab + kt,            As + tid * 8);
    gload16(Ab + kt + 64 * K,   As + 2048 + tid * 8);
    gload16(Bb + kt,            Bs + tid * 8);
    gload16(Bb + kt + 64 * K,   Bs + 2048 + tid * 8);
    __syncthreads();
    short8 a[4], b[4];
#pragma unroll
    for (int m = 0; m < 4; ++m)
      a[m] = *(const short8*)&As[(wr * 64 + m * 16 + lo) * 32 + hi * 8];
#pragma unroll
    for (int n = 0; n < 4; ++n)
      b[n] = *(const short8*)&Bs[(wc * 64 + n * 16 + lo) * 32 + hi * 8];
#pragma unroll
    for (int m = 0; m < 4; ++m)
#pragma unroll
      for (int n = 0; n < 4; ++n)
        acc[m][n] = mfma16(a[m], b[n], acc[m][n]);
    __syncthreads();
  }
  int tg0 = (bm * 128 + wr * 64) & 4095;
  int bb  = (bm * 128) >> 12;
  if (wc == 0) {                                   // K head: RMS + RoPE
    float w0 = kw[lo], w1 = kw[16 + lo], w2 = kw[32 + lo], w3 = kw[48 + lo];
    const float2* tb = (const float2*)trig;
#pragma unroll
    for (int m = 0; m < 4; ++m)
#pragma unroll
      for (int r = 0; r < 4; ++r) {
        float x0 = acc[m][0][r], x1 = acc[m][1][r];
        float x2 = acc[m][2][r], x3 = acc[m][3][r];
        float ss = x0 * x0 + x1 * x1 + x2 * x2 + x3 * x3;
        ss += __shfl_xor(ss, 1); ss += __shfl_xor(ss, 2);
        ss += __shfl_xor(ss, 4); ss += __shfl_xor(ss, 8);
        float rn = rsqrtf(ss * 0.015625f + 1e-6f);
        x0 *= rn * w0; x1 *= rn * w1; x2 *= rn * w2; x3 *= rn * w3;
        int tp = tg0 + m * 16 + hi * 4 + r;
        float2 cs0 = tb[tp * 32 + lo];
        float2 cs1 = tb[tp * 32 + 16 + lo];
        float o0 = x0 * cs0.x - x2 * cs0.y;
        float o1 = x1 * cs1.x - x3 * cs1.y;
        float o2 = x2 * cs0.x + x0 * cs0.y;
        float o3 = x3 * cs1.x + x1 * cs1.y;
        size_t tb_ = ((size_t)bb * 4096 + tp) * 64;
        kb2[tb_ + lo]      = (short)f2bf(o0);
        kb2[tb_ + 16 + lo] = (short)f2bf(o1);
        kb2[tb_ + 32 + lo] = (short)f2bf(o2);
        kb2[tb_ + 48 + lo] = (short)f2bf(o3);
      }
  } else {                                         // V: transpose to [d][t]
#pragma unroll
    for (int m = 0; m < 4; ++m)
#pragma unroll
      for (int nf = 0; nf < 4; ++nf) {
        int dd = nf * 16 + lo;
        short4 o;
        o.x = (short)f2bf(acc[m][nf][0]);
        o.y = (short)f2bf(acc[m][nf][1]);
        o.z = (short)f2bf(acc[m][nf][2]);
        o.w = (short)f2bf(acc[m][nf][3]);
        *(short4*)&vtg[((size_t)(bb * 64 + dd)) * 4096 + tg0 + m * 16 + hi * 4] = o;
      }
  }
}

// ---------------- kernel: 256x256x64 bf16 GEMM, depth-1 pipeline ------------
// ONE __syncthreads per K-tile: stage jt+1 into buffer d^1 at tile START,
// compute all of jt from buffer d, sync (drains DMA that had a full tile of
// latency slack). No mid-tile barriers, no staging into the active buffer.
// mode 1 (Q): fused RMS+RoPE epilogue, direct global stores -> qb2.
__global__ __launch_bounds__(512, 2) void k_gemm256(
    const short* __restrict__ A, const short* __restrict__ Bt,
    void* __restrict__ Cout, int M, int N, int K, int outBf16,
    const float* __restrict__ trig, const float* __restrict__ qw,
    short* __restrict__ qb2, int mode) {
  __shared__ short sm[65536];                       // 128 KiB (2 x 64 KB K-tile)
  int nbn = N >> 8;
  int nwg = (M >> 8) * nbn;
  int bid = blockIdx.x;
  int swz = (bid & 7) * (nwg >> 3) + (bid >> 3);    // XCD swizzle (nwg % 8 == 0)
  int bm = swz / nbn, bn = swz % nbn;
  int tid = threadIdx.x, wid = tid >> 6, lane = tid & 63;
  int wm = wid >> 2, wn = wid & 3;
  int lo = lane & 15, hi = lane >> 4;
  int NT = K >> 6;                                  // # K-tiles (BK=64)

  int r0 = tid >> 3, dc = tid & 7;
  int sc = dc ^ (r0 & 7);                           // pre-swizzled source chunk
  const short* aS0 = A  + (size_t)(bm * 256 + r0) * K + sc * 8;
  const short* bS0 = Bt + (size_t)(bn * 256 + r0) * K + sc * 8;
  size_t hstep = (size_t)128 * K;

  // stage one full K-tile (A+B, 4 halves, 8 gloads) into dbuf d
  auto stageAll = [&](int jt, int d) {
#pragma unroll
    for (int mat = 0; mat < 2; ++mat)
#pragma unroll
      for (int h = 0; h < 2; ++h) {
        const short* s = (mat ? bS0 : aS0) + (size_t)h * hstep + jt * 64;
        short* l = sm + d * 32768 + mat * 16384 + h * 8192;
        gload16(s,                  l + tid * 8);
        gload16(s + (size_t)64 * K, l + 4096 + tid * 8);
      }
  };

  int aRd[2];
#pragma unroll
  for (int kk = 0; kk < 2; ++kk)
    aRd[kk] = lo * 64 + (((kk << 2) | hi) ^ (lo & 7)) * 8;

  short8 Afr[8][2];
  short8 Bfr[4][2];
  f32x4 acc[8][4] = {};

  auto rdA = [&](int d, int m0) {
    int base = d * 32768 + wm * 8192;
#pragma unroll
    for (int m = 0; m < 4; ++m)
#pragma unroll
      for (int kk = 0; kk < 2; ++kk)
        Afr[m0 + m][kk] = *(const short8*)&sm[base + (m0 + m) * 1024 + aRd[kk]];
  };
  auto rdB = [&](int d, int n0) {
    int base = d * 32768 + 16384 + (wn >> 1) * 8192 + (wn & 1) * 4096;
#pragma unroll
    for (int nf = 0; nf < 2; ++nf)
#pragma unroll
      for (int kk = 0; kk < 2; ++kk)
        Bfr[n0 + nf][kk] = *(const short8*)&sm[base + (n0 + nf) * 1024 + aRd[kk]];
  };
  auto quad = [&](int m0, int n0) {                 // 16 MFMA
    __builtin_amdgcn_s_setprio(1);
#pragma unroll
    for (int m = 0; m < 4; ++m)
#pragma unroll
      for (int j = 0; j < 2; ++j)
#pragma unroll
        for (int kk = 0; kk < 2; ++kk)
          acc[m0 + m][n0 + j] = mfma16(Afr[m0 + m][kk], Bfr[n0 + j][kk],
                                       acc[m0 + m][n0 + j]);
    __builtin_amdgcn_s_setprio(0);
  };

  stageAll(0, 0);
  __syncthreads();                                  // drain prologue DMA

#pragma unroll 2
  for (int jt = 0; jt < NT; ++jt) {
    int d = jt & 1;
    if (jt + 1 < NT) stageAll(jt + 1, d ^ 1);       // DMA issued at tile START
    rdA(d, 0); rdB(d, 0); rdB(d, 2);
    quad(0, 0); quad(0, 2);
    rdA(d, 4);
    quad(4, 0); quad(4, 2);
    __syncthreads();                                // one barrier+drain per tile
  }

  if (mode == 1) {
    // ---- fused Q epilogue: RMS+RoPE, direct global stores (no LDS)
    int tg0 = (bm * 256 + wm * 128) & 4095;
    int bb  = (bm * 256) >> 12;
    int hh  = bn * 4 + wn;
    float w0 = qw[lo], w1 = qw[16 + lo], w2 = qw[32 + lo], w3 = qw[48 + lo];
    short* dst = qb2 + (size_t)((bb * 16 + hh) * 4096) * 64;
    const float2* tb = (const float2*)trig;
#pragma unroll
    for (int m = 0; m < 8; ++m)
#pragma unroll
      for (int r = 0; r < 4; ++r) {
        float x0 = acc[m][0][r], x1 = acc[m][1][r];
        float x2 = acc[m][2][r], x3 = acc[m][3][r];
        float ss = x0 * x0 + x1 * x1 + x2 * x2 + x3 * x3;
        ss += __shfl_xor(ss, 1); ss += __shfl_xor(ss, 2);
        ss += __shfl_xor(ss, 4); ss += __shfl_xor(ss, 8);
        float rn = rsqrtf(ss * 0.015625f + 1e-6f);
        x0 *= rn * w0; x1 *= rn * w1; x2 *= rn * w2; x3 *= rn * w3;
        int tp = tg0 + m * 16 + hi * 4 + r;
        float2 cs0 = tb[tp * 32 + lo];
        float2 cs1 = tb[tp * 32 + 16 + lo];
        float o0 = x0 * cs0.x - x2 * cs0.y;
        float o1 = x1 * cs1.x - x3 * cs1.y;
        float o2 = x2 * cs0.x + x0 * cs0.y;
        float o3 = x3 * cs1.x + x1 * cs1.y;
        size_t tb_ = (size_t)tp * 64;
        dst[tb_ + lo]      = (short)f2bf(o0);
        dst[tb_ + 16 + lo] = (short)f2bf(o1);
        dst[tb_ + 32 + lo] = (short)f2bf(o2);
        dst[tb_ + 48 + lo] = (short)f2bf(o3);
      }
    return;
  }

  // ---- mode 0: plain C write. layout col = lane&15, row = (lane>>4)*4 + reg
  int row0 = bm * 256 + wm * 128 + hi * 4;
  int col0 = bn * 256 + wn * 64 + lo;
  if (outBf16) {
    short* C = (short*)Cout;
#pragma unroll
    for (int m = 0; m < 8; ++m)
#pragma unroll
      for (int nf = 0; nf < 4; ++nf)
#pragma unroll
        for (int r = 0; r < 4; ++r)
          C[(size_t)(row0 + m * 16 + r) * N + col0 + nf * 16] = (short)f2bf(acc[m][nf][r]);
  } else {
    float* C = (float*)Cout;
#pragma unroll
    for (int m = 0; m < 8; ++m)
#pragma unroll
      for (int nf = 0; nf < 4; ++nf)
#pragma unroll
        for (int r = 0; r < 4; ++r)
          C[(size_t)(row0 + m * 16 + r) * N + col0 + nf * 16] = acc[m][nf][r];
  }
}

// ---------------- kernel: blocked sliding-window attention (swapped QK^T) ----
__global__ __launch_bounds__(256, 4) void k_attn(const short* __restrict__ qb,
                                                 const short* __restrict__ kb,
                                                 const short* __restrict__ vtg,
                                                 short* __restrict__ y) {
  __shared__ __align__(16) char smem[33792];
  short* ks  = (short*)smem;            // [128 key][64 d], chunk-XOR swizzled
  short* vts = (short*)(smem + 16384);  // [64 d][128 key], chunk-XOR swizzled
  int bid = blockIdx.x;
  int swz = (bid & 7) * 256 + (bid >> 3);          // XCD swizzle
  int h = swz & 15, n = (swz >> 4) & 31, b = swz >> 9;
  int tid = threadIdx.x, wid = tid >> 6, lane = tid & 63;
  int lo = lane & 31, hi = lane >> 5;

  const short* qrow = qb + (size_t)((b * 16 + h) * 4096 + n * 128 + wid * 32 + lo) * 64;
  short8 aq[4];
#pragma unroll
  for (int s = 0; s < 4; ++s) aq[s] = *(const short8*)(qrow + s * 16 + hi * 8);

  f32x16 O0 = {}, O1 = {};                         // O^T: rows d / d+32, col q
  float mrun = -1e30f, lrun = 0.f;
  int qr = wid * 32 + lo;
  const float SC = 0.125f * 1.4426950408889634f;   // scale * log2(e)

  for (int hf = (n == 0) ? 1 : 0; hf < 2; ++hf) {  // n==0: half0 fully masked
    int tg = (n - 1 + hf) * 128;                   // first key token (within b)
#pragma unroll
    for (int p = 0; p < 4; ++p) {
      int idx = p * 256 + tid;
      int r = idx >> 3, dc = idx & 7;
      gload16(kb + (size_t)(b * 4096 + tg + r) * 64 + ((dc ^ (r & 7)) << 3),
              ks + idx * 8);
    }
#pragma unroll
    for (int p = 0; p < 4; ++p) {
      int idx = p * 256 + tid;
      int dd = idx >> 4, s = idx & 15;
      gload16(vtg + (size_t)(b * 64 + dd) * 4096 + tg + ((s ^ (dd & 7)) << 3),
              vts + idx * 8);
    }
    __syncthreads();

#pragma unroll
    for (int mt = 0; mt < 4; ++mt) {
      f32x16 S = {};
      int r = mt * 32 + lo;
#pragma unroll
      for (int kst = 0; kst < 4; ++kst) {
        short8 kf = *(const short8*)&ks[r * 64 + ((((kst << 1) | hi) ^ (r & 7)) << 3)];
        S = mfma32(kf, aq[kst], S);
      }
#pragma unroll
      for (int rr = 0; rr < 16; ++rr) {
        int kg = hf * 128 + mt * 32 + (rr & 3) + ((rr >> 2) << 3) + (hi << 2);
        S[rr] = (kg >= qr && kg <= qr + 128) ? S[rr] * SC : -30000.f;
      }
      float pmax = S[0];
#pragma unroll
      for (int rr = 1; rr < 16; ++rr) pmax = fmaxf(pmax, S[rr]);
      pmax = fmaxf(pmax, __shfl_xor(pmax, 32));
      if (!__all(pmax - mrun <= 8.f)) {
        float mn = fmaxf(mrun, pmax);
        float al = exp2f(mrun - mn);
        lrun *= al; mrun = mn;
#pragma unroll
        for (int rr = 0; rr < 16; ++rr) { O0[rr] *= al; O1[rr] *= al; }
      }
      float ls = 0.f;
#pragma unroll
      for (int rr = 0; rr < 16; ++rr) { S[rr] = exp2f(S[rr] - mrun); ls += S[rr]; }
      ls += __shfl_xor(ls, 32);
      lrun += ls;
#pragma unroll
      for (int h2 = 0; h2 < 2; ++h2) {
        int b0 = h2 * 8;
        unsigned pk0 = cvtpk(S[b0 + 0], S[b0 + 1]);
        unsigned pk1 = cvtpk(S[b0 + 2], S[b0 + 3]);
        unsigned pk2 = cvtpk(S[b0 + 4], S[b0 + 5]);
        unsigned pk3 = cvtpk(S[b0 + 6], S[b0 + 7]);
        asm("v_permlane32_swap_b32 %0, %1" : "+v"(pk0), "+v"(pk2));
        asm("v_permlane32_swap_b32 %0, %1" : "+v"(pk1), "+v"(pk3));
        uint4v uw; uw.x = pk0; uw.y = pk1; uw.z = pk2; uw.w = pk3;
        short8 pb = __builtin_bit_cast(short8, uw);
        int kc = mt * 4 + h2 * 2 + hi;
        short8 vb0 = *(const short8*)&vts[lo * 128 + ((kc ^ (lo & 7)) << 3)];
        short8 vb1 = *(const short8*)&vts[(32 + lo) * 128 + ((kc ^ (lo & 7)) << 3)];
        O0 = mfma32(vb0, pb, O0);
        O1 = mfma32(vb1, pb, O1);
      }
    }
    __syncthreads();
  }

  float inv = 1.f / lrun;
  float* ot = (float*)smem + wid * 2112;           // [64 d][33] per wave
#pragma unroll
  for (int r = 0; r < 16; ++r) {
    int d0 = (r & 3) + ((r >> 2) << 3) + (hi << 2);
    ot[d0 * 33 + lo]        = O0[r] * inv;
    ot[(d0 + 32) * 33 + lo] = O1[r] * inv;
  }
  __syncthreads();
  int tok = lane >> 3, dc = lane & 7;
#pragma unroll
  for (int g = 0; g < 4; ++g) {
    int q = g * 8 + tok;
    short8 o8;
#pragma unroll
    for (int jj = 0; jj < 8; ++jj)
      o8[jj] = (short)f2bf(ot[(dc * 8 + jj) * 33 + q]);
    *(short8*)&y[(size_t)(b * 4096 + n * 128 + wid * 32 + q) * 1024 + h * 64 + dc * 8] = o8;
  }
}

// ---------------- launch ----------------
extern "C" void kernel_launch(void* const* d_in, const int* in_sizes, int n_in,
                              void* d_out, int out_size, void* d_ws, size_t ws_size,
                              hipStream_t stream) {
  const float* x      = (const float*)d_in[0];
  const int*   pos    = (const int*)d_in[1];
  const float* w_attn = (const float*)d_in[2];
  const float* w_proj = (const float*)d_in[3];
  const float* qw     = (const float*)d_in[4];
  const float* kw     = (const float*)d_in[5];

  char* ws = (char*)d_ws;
  short* xb   = (short*)ws;                         // 33,554,432 B (aliased as y later)
  short* wabt = (short*)(ws + 33554432);            //  2,359,296 B (1152 x 1024)
  short* wpbt = (short*)(ws + 35913728);            //  2,097,152 B
  short* qb2  = (short*)(ws + 38010880);            // 33,554,432 B
  short* kb2  = (short*)(ws + 71565312);            //  2,097,152 B
  short* vtg  = (short*)(ws + 73662464);            //  2,097,152 B
  float* trig = (float*)(ws + 75759616);            //  1,048,576 B (cos,sin pairs)
  short* ybuf = xb;                                 // xb dead after Q/KV GEMMs

  hipLaunchKernelGGL(k_prep, dim3(16384 + 1152 + 1024 + 512), dim3(256), 0, stream,
                     x, xb, w_attn, wabt, w_proj, wpbt, pos, trig);
  hipLaunchKernelGGL(k_gemmkv, dim3(128), dim3(256), 0, stream, xb,
                     wabt + (size_t)1024 * 1024, trig, kw, kb2, vtg);
  hipLaunchKernelGGL(k_gemm256, dim3(256), dim3(512), 0, stream, xb, wabt,
                     (void*)nullptr, 16384, 1024, 1024, 1, trig, qw, qb2, 1);
  hipLaunchKernelGGL(k_attn, dim3(2048), dim3(256), 0, stream, qb2, kb2, vtg, ybuf);
  hipLaunchKernelGGL(k_gemm256, dim3(256), dim3(512), 0, stream, ybuf, wpbt, d_out,
                     16384, 1024, 1024, 0,
                     (const float*)nullptr, (const float*)nullptr,
                     (short*)nullptr, 0);
}